// Round 5
// baseline (433.811 us; speedup 1.0000x reference)
//
#include <hip/hip_runtime.h>
#include <hip/hip_bf16.h>

// GCN 2-layer: h = relu(Anorm @ (x@W1) + b1); out = Anorm @ (h@W2) + b2
// R14 changes vs R13:
//  - Lesson R9-R13: gather path saturates at ~2.9 TB/s L2-miss BW;
//    FETCH (186MB) = 8 XCDs x compulsory distinct-row misses. Only lever
//    left: fewer miss bytes via FEATURE-SPLIT + real XCD affinity.
//  - agg128h / agg64h: persistent kernels; blocks read physical XCD id
//    (s_getreg HW_REG_XCC_ID), XCDs 0-3 own feature-half 0, XCDs 4-7
//    half 1; per-half atomic work cursors + stealing (XCC is perf hint
//    only; wrong id still correct). Per-XCD distinct bytes halve.
//  - GEMM2 un-fused again (split breaks the in-block MFMA tail):
//    agg128h writes g bf16; gemm_mfma<64,false> computes h2q.
//  - Gather unroll back to proven 8-deep (VGPR<=64, no occupancy cliff).

#define NTHREADS 256
#define BSH 8                 // bucket = dst >> 8 (256 nodes/bucket)
#define NBMAX 512
#define FC_CAP 8192           // LDS edge cache per bucket

typedef unsigned int uint;
typedef unsigned short ushort;
typedef __attribute__((ext_vector_type(8))) short short8;
typedef __attribute__((ext_vector_type(4))) float floatx4;

__device__ __forceinline__ uint pack_bf16(float a, float b) {
    __hip_bfloat162 h = __float22bfloat162_rn(make_float2(a, b));
    return *reinterpret_cast<uint*>(&h);
}
__device__ __forceinline__ float bf16_lo(uint q) { return __uint_as_float(q << 16); }
__device__ __forceinline__ float bf16_hi(uint q) { return __uint_as_float(q & 0xffff0000u); }

__device__ __forceinline__ int xcd_id() {
    uint x;
    asm volatile("s_getreg_b32 %0, hwreg(HW_REG_XCC_ID)" : "=s"(x));
    return (int)(x & 7u);
}

// ---------- coarse bucket histogram only (no per-node atomics) ----------
__global__ __launch_bounds__(256) void bucket_hist_kernel(
    const int* __restrict__ dst, int* __restrict__ bcnt, int e, int nb) {
    __shared__ int hist[NBMAX];
    int t = threadIdx.x;
    for (int b = t; b < nb; b += 256) hist[b] = 0;
    __syncthreads();
    int e0 = blockIdx.x * 2048;
#pragma unroll
    for (int v = 0; v < 2; v++) {
        int gi = e0 + t * 8 + v * 4;
        if (gi + 3 < e) {
            int4 d4 = *(const int4*)&dst[gi];
            atomicAdd(&hist[d4.x >> BSH], 1);
            atomicAdd(&hist[d4.y >> BSH], 1);
            atomicAdd(&hist[d4.z >> BSH], 1);
            atomicAdd(&hist[d4.w >> BSH], 1);
        } else {
            for (int j = 0; j < 4; j++)
                if (gi + j < e) atomicAdd(&hist[dst[gi + j] >> BSH], 1);
        }
    }
    __syncthreads();
    for (int b = t; b < nb; b += 256) {
        int v = hist[b];
        if (v) atomicAdd(&bcnt[b], v);
    }
}

// ---------- bucket scan (nb <= 512, single block of 512) ----------
__global__ void bucket_scan(const int* __restrict__ bcnt, int* __restrict__ bstart,
                            int* __restrict__ bcursor, int nb) {
    __shared__ int buf[NBMAX];
    int t = threadIdx.x;
    int v = (t < nb) ? bcnt[t] : 0;
    buf[t] = v;
    __syncthreads();
    int x = v;
    for (int off = 1; off < NBMAX; off <<= 1) {
        int y = (t >= off) ? buf[t - off] : 0;
        __syncthreads();
        x += y;
        buf[t] = x;
        __syncthreads();
    }
    if (t < nb) {
        bstart[t] = x - v;
        bcursor[t] = x - v;
    }
}

// ---------- coarse partition: staged[] = packed (src<<8|dloc) by bucket ----------
__global__ __launch_bounds__(256) void partition_kernel(
    const int* __restrict__ src, const int* __restrict__ dst,
    int* __restrict__ bcursor, uint* __restrict__ staged, int e, int nb) {
    __shared__ uint eP[2048];        // packed (src<<8 | dst&255)
    __shared__ ushort eB[2048];      // bucket id (0xFFFF = invalid)
    __shared__ int hist[NBMAX];
    __shared__ int base[NBMAX];
    int t = threadIdx.x;
    int e0 = blockIdx.x * 2048;

    for (int b = t; b < nb; b += 256) hist[b] = 0;
    __syncthreads();
#pragma unroll
    for (int v = 0; v < 2; v++) {
        int li = t * 8 + v * 4;
        int gi = e0 + li;
        int4 s4, d4;
        if (gi + 3 < e) {
            s4 = *(const int4*)&src[gi];
            d4 = *(const int4*)&dst[gi];
        } else {
            const int* sp = &src[gi];
            const int* dp = &dst[gi];
            s4.x = (gi + 0 < e) ? sp[0] : 0;  d4.x = (gi + 0 < e) ? dp[0] : -1;
            s4.y = (gi + 1 < e) ? sp[1] : 0;  d4.y = (gi + 1 < e) ? dp[1] : -1;
            s4.z = (gi + 2 < e) ? sp[2] : 0;  d4.z = (gi + 2 < e) ? dp[2] : -1;
            s4.w = (gi + 3 < e) ? sp[3] : 0;  d4.w = (gi + 3 < e) ? dp[3] : -1;
        }
        uint4 p4;
        p4.x = ((uint)s4.x << 8) | ((uint)d4.x & 255u);
        p4.y = ((uint)s4.y << 8) | ((uint)d4.y & 255u);
        p4.z = ((uint)s4.z << 8) | ((uint)d4.z & 255u);
        p4.w = ((uint)s4.w << 8) | ((uint)d4.w & 255u);
        *(uint4*)&eP[li] = p4;
        eB[li + 0] = (d4.x >= 0) ? (ushort)(d4.x >> BSH) : (ushort)0xFFFF;
        eB[li + 1] = (d4.y >= 0) ? (ushort)(d4.y >> BSH) : (ushort)0xFFFF;
        eB[li + 2] = (d4.z >= 0) ? (ushort)(d4.z >> BSH) : (ushort)0xFFFF;
        eB[li + 3] = (d4.w >= 0) ? (ushort)(d4.w >> BSH) : (ushort)0xFFFF;
        if (d4.x >= 0) atomicAdd(&hist[d4.x >> BSH], 1);
        if (d4.y >= 0) atomicAdd(&hist[d4.y >> BSH], 1);
        if (d4.z >= 0) atomicAdd(&hist[d4.z >> BSH], 1);
        if (d4.w >= 0) atomicAdd(&hist[d4.w >> BSH], 1);
    }
    __syncthreads();
    for (int b = t; b < nb; b += 256) {
        int v = hist[b];
        base[b] = v ? atomicAdd(&bcursor[b], v) : 0;
        hist[b] = 0;   // reset for rank pass
    }
    __syncthreads();
#pragma unroll
    for (int i = 0; i < 8; i++) {
        int li = t + i * 256;
        ushort bb = eB[li];
        if (bb != (ushort)0xFFFF) {
            int r = atomicAdd(&hist[bb], 1);
            staged[base[bb] + r] = eP[li];
        }
    }
}

// ---------- per-bucket fused CSR: count+scan -> meta/dinv, LDS-cached fill ----------
__global__ __launch_bounds__(256) void fine_csr_kernel(
    const uint* __restrict__ staged, const int* __restrict__ bstart,
    const int* __restrict__ bcnt, int4* __restrict__ meta,
    float* __restrict__ dinv, int* __restrict__ rec, int n) {
    __shared__ uint eL[FC_CAP];      // 32 KB edge cache
    __shared__ int lcnt[256];
    __shared__ int tsum[256];
    int b = blockIdx.x;
    int t = threadIdx.x;
    lcnt[t] = 0;
    __syncthreads();
    int s0 = bstart[b];
    int m = bcnt[b];
    for (int i = t; i < m; i += 256) {
        uint pk = staged[s0 + i];
        if (i < FC_CAP) eL[i] = pk;
        atomicAdd(&lcnt[pk & 255u], 1);
    }
    __syncthreads();
    int v = lcnt[t];
    tsum[t] = v;
    __syncthreads();
    int x = v;
    for (int off = 1; off < 256; off <<= 1) {
        int y = (t >= off) ? tsum[t - off] : 0;
        __syncthreads();
        x += y;
        tsum[t] = x;
        __syncthreads();
    }
    int excl = x - v;
    int node = (b << BSH) + t;
    if (node < n) {
        float di = rsqrtf((float)v + 1.0f);
        dinv[node] = di;
        meta[node] = make_int4(s0 + excl, v, __float_as_int(di), __float_as_int(di * di));
    }
    lcnt[t] = s0 + excl;             // repurpose as absolute cursor
    __syncthreads();
    // fill: rec[pos] = src (edges come from LDS cache)
    for (int i = t; i < m; i += 256) {
        uint pk = (i < FC_CAP) ? eL[i] : staged[s0 + i];
        int pos = atomicAdd(&lcnt[pk & 255u], 1);
        rec[pos] = (int)(pk >> 8);
    }
}

// ---------- bf16 MFMA GEMM: Cq[n,COLS](bf16) = dscale[r] * (X[n,128] @ W[128,COLS]) ----------
template <int COLS, bool XF32>
__global__ __launch_bounds__(256) void gemm_mfma(const void* __restrict__ Xv,
                                                 const float* __restrict__ W,
                                                 uint* __restrict__ Cq,
                                                 const float* __restrict__ dscale,
                                                 int n) {
    __shared__ ushort sX[64 * 128];
    __shared__ ushort sWT[COLS * 128];
    int t = threadIdx.x;
    int rbase = blockIdx.x * 64;

    if (XF32) {
        const float* X = (const float*)Xv;
#pragma unroll
        for (int i = 0; i < 8; i++) {
            int f = t + 256 * i;
            int r = f >> 5;
            int c4 = f & 31;
            float4 v = make_float4(0.f, 0.f, 0.f, 0.f);
            int gr = rbase + r;
            if (gr < n) v = *(const float4*)(X + (size_t)gr * 128 + c4 * 4);
            uint lo = pack_bf16(v.x, v.y);
            uint hi = pack_bf16(v.z, v.w);
            int chunk = c4 >> 1;
            int sub = (c4 & 1) * 4;
            int off = r * 128 + (((chunk ^ (r & 15)) << 3) + sub);
            *(uint2*)&sX[off] = make_uint2(lo, hi);
        }
    } else {
        const ushort* X = (const ushort*)Xv;
#pragma unroll
        for (int i = 0; i < 4; i++) {
            int f = t + 256 * i;
            int r = f >> 4;
            int chunk = f & 15;
            uint4 v = make_uint4(0, 0, 0, 0);
            int gr = rbase + r;
            if (gr < n) v = *(const uint4*)(X + (size_t)gr * 128 + chunk * 8);
            int off = r * 128 + ((chunk ^ (r & 15)) << 3);
            *(uint4*)&sX[off] = v;
        }
    }
    {
        constexpr int UNITS = 64 * (COLS / 4);
        constexpr int PER_T = UNITS / 256;
#pragma unroll
        for (int i = 0; i < PER_T; i++) {
            int u = t + 256 * i;
            int kp = u / (COLS / 4);
            int n4 = u % (COLS / 4);
            int k = kp * 2;
            float4 w0 = *(const float4*)(W + (size_t)k * COLS + n4 * 4);
            float4 w1 = *(const float4*)(W + (size_t)(k + 1) * COLS + n4 * 4);
            int chunk = k >> 3;
            int sub = k & 7;
            const float* a0 = (const float*)&w0;
            const float* a1 = (const float*)&w1;
#pragma unroll
            for (int j = 0; j < 4; j++) {
                int nn = n4 * 4 + j;
                uint pk = pack_bf16(a0[j], a1[j]);
                int off = nn * 128 + (((chunk ^ (nn & 15)) << 3) + sub);
                *(uint*)&sWT[off] = pk;
            }
        }
    }
    __syncthreads();

    int lane = t & 63;
    int wave = t >> 6;
    int m = lane & 15;
    int q = lane >> 4;
    int r0 = wave * 16;

    floatx4 acc[COLS / 16];
#pragma unroll
    for (int c = 0; c < COLS / 16; c++) acc[c] = (floatx4){0.f, 0.f, 0.f, 0.f};

#pragma unroll
    for (int ks = 0; ks < 4; ks++) {
        int rr = r0 + m;
        int ca = (ks * 4 + q) ^ (rr & 15);
        short8 afrag = *(const short8*)&sX[rr * 128 + (ca << 3)];
#pragma unroll
        for (int c = 0; c < COLS / 16; c++) {
            int nn = c * 16 + m;
            int cb = (ks * 4 + q) ^ (nn & 15);
            short8 bfrag = *(const short8*)&sWT[nn * 128 + (cb << 3)];
            acc[c] = __builtin_amdgcn_mfma_f32_16x16x32_bf16(bfrag, afrag, acc[c], 0, 0, 0);
        }
    }

    int gr = rbase + r0 + m;
    if (gr < n) {
        float sc = dscale[gr];
#pragma unroll
        for (int c = 0; c < COLS / 16; c++) {
            uint2 pk;
            pk.x = pack_bf16(acc[c][0] * sc, acc[c][1] * sc);
            pk.y = pack_bf16(acc[c][2] * sc, acc[c][3] * sc);
            *(uint2*)&Cq[(size_t)gr * (COLS / 2) + c * 8 + q * 2] = pk;
        }
    }
}

// ---------- layer-1 aggregation, FEATURE-SPLIT + XCD-affine persistent ----------
// Work unit = (half, 64 nodes). XCDs 0-3 prefer half 0, XCDs 4-7 half 1;
// per-half atomic cursor + stealing. Eighth-wave per node-half:
// 8 lanes x uint4 = 128B = 64 feats. g = relu(di*acc + b1) -> bf16.
__global__ __launch_bounds__(512) void agg128h(
    const uint* __restrict__ hq, const int* __restrict__ rec,
    const int4* __restrict__ meta, const float* __restrict__ bias,
    int* __restrict__ wcur, uint* __restrict__ gq, int n) {
    __shared__ int2 sWk;
    int t = threadIdx.x;
    const int NG = (n + 63) >> 6;
    int myhf = (xcd_id() >> 2) & 1;
    const uint4* h4 = (const uint4*)hq;    // hq row = 16 uint4

    for (;;) {
        if (t == 0) {
            int h = myhf;
            int g = atomicAdd(&wcur[h], 1);
            if (g >= NG) { h ^= 1; g = atomicAdd(&wcur[h], 1); }
            sWk = make_int2(h, g);
        }
        __syncthreads();
        int hf = sWk.x;
        int ng = sWk.y;
        __syncthreads();
        if (ng >= NG) break;

        int w = (ng << 6) + (t >> 3);
        int fl = t & 7;
        bool valid = w < n;
        int ws = valid ? w : 0;
        int4 mt = meta[ws];
        int j0 = mt.x;
        int deg = valid ? mt.y : 0;
        float di = __int_as_float(mt.z);
        int off = hf * 8 + fl;             // uint4 offset within row

        uint4 qs = h4[(size_t)ws * 16 + off];
        float a0 = bf16_lo(qs.x), a1 = bf16_hi(qs.x);
        float a2 = bf16_lo(qs.y), a3 = bf16_hi(qs.y);
        float a4 = bf16_lo(qs.z), a5 = bf16_hi(qs.z);
        float a6 = bf16_lo(qs.w), a7 = bf16_hi(qs.w);

        const int* rp = rec + j0;
        int tt = 0;
        for (; tt + 8 <= deg; tt += 8) {
            int s[8]; uint4 q[8];
#pragma unroll
            for (int u = 0; u < 8; u++) s[u] = rp[tt + u];
#pragma unroll
            for (int u = 0; u < 8; u++) q[u] = h4[(size_t)s[u] * 16 + off];
#pragma unroll
            for (int u = 0; u < 8; u++) {
                a0 += bf16_lo(q[u].x); a1 += bf16_hi(q[u].x);
                a2 += bf16_lo(q[u].y); a3 += bf16_hi(q[u].y);
                a4 += bf16_lo(q[u].z); a5 += bf16_hi(q[u].z);
                a6 += bf16_lo(q[u].w); a7 += bf16_hi(q[u].w);
            }
        }
        for (; tt + 2 <= deg; tt += 2) {
            int s0i = rp[tt], s1i = rp[tt + 1];
            uint4 q0 = h4[(size_t)s0i * 16 + off];
            uint4 q1 = h4[(size_t)s1i * 16 + off];
            a0 += bf16_lo(q0.x) + bf16_lo(q1.x);
            a1 += bf16_hi(q0.x) + bf16_hi(q1.x);
            a2 += bf16_lo(q0.y) + bf16_lo(q1.y);
            a3 += bf16_hi(q0.y) + bf16_hi(q1.y);
            a4 += bf16_lo(q0.z) + bf16_lo(q1.z);
            a5 += bf16_hi(q0.z) + bf16_hi(q1.z);
            a6 += bf16_lo(q0.w) + bf16_lo(q1.w);
            a7 += bf16_hi(q0.w) + bf16_hi(q1.w);
        }
        if (tt < deg) {
            int s = rp[tt];
            uint4 q0 = h4[(size_t)s * 16 + off];
            a0 += bf16_lo(q0.x); a1 += bf16_hi(q0.x);
            a2 += bf16_lo(q0.y); a3 += bf16_hi(q0.y);
            a4 += bf16_lo(q0.z); a5 += bf16_hi(q0.z);
            a6 += bf16_lo(q0.w); a7 += bf16_hi(q0.w);
        }

        if (valid) {
            int fb = hf * 64 + 8 * fl;
            float4 bb0 = *(const float4*)&bias[fb];
            float4 bb1 = *(const float4*)&bias[fb + 4];
            uint4 pkv;
            pkv.x = pack_bf16(fmaxf(di * a0 + bb0.x, 0.f), fmaxf(di * a1 + bb0.y, 0.f));
            pkv.y = pack_bf16(fmaxf(di * a2 + bb0.z, 0.f), fmaxf(di * a3 + bb0.w, 0.f));
            pkv.z = pack_bf16(fmaxf(di * a4 + bb1.x, 0.f), fmaxf(di * a5 + bb1.y, 0.f));
            pkv.w = pack_bf16(fmaxf(di * a6 + bb1.z, 0.f), fmaxf(di * a7 + bb1.w, 0.f));
            ((uint4*)gq)[(size_t)w * 16 + off] = pkv;
        }
    }
}

// ---------- layer-2 aggregation, FEATURE-SPLIT + XCD-affine persistent ----------
// Work unit = (half, 128 nodes). 4 lanes x uint4 = 64B = 32 feats
// (one cache line per gather). out = di*acc + b2 (f32).
__global__ __launch_bounds__(512) void agg64h(
    const uint* __restrict__ h2q, const int* __restrict__ rec,
    const int4* __restrict__ meta, const float* __restrict__ bias,
    int* __restrict__ wcur, float* __restrict__ out, int n) {
    __shared__ int2 sWk;
    int t = threadIdx.x;
    const int NG = (n + 127) >> 7;
    int myhf = (xcd_id() >> 2) & 1;
    const uint4* h4 = (const uint4*)h2q;   // h2q row = 8 uint4

    for (;;) {
        if (t == 0) {
            int h = myhf;
            int g = atomicAdd(&wcur[h], 1);
            if (g >= NG) { h ^= 1; g = atomicAdd(&wcur[h], 1); }
            sWk = make_int2(h, g);
        }
        __syncthreads();
        int hf = sWk.x;
        int ng = sWk.y;
        __syncthreads();
        if (ng >= NG) break;

        int w = (ng << 7) + (t >> 2);
        int fl = t & 3;
        bool valid = w < n;
        int ws = valid ? w : 0;
        int4 mt = meta[ws];
        int j0 = mt.x;
        int deg = valid ? mt.y : 0;
        float di = __int_as_float(mt.z);
        int off = hf * 4 + fl;             // uint4 offset within row

        uint4 qs = h4[(size_t)ws * 8 + off];
        float a0 = bf16_lo(qs.x), a1 = bf16_hi(qs.x);
        float a2 = bf16_lo(qs.y), a3 = bf16_hi(qs.y);
        float a4 = bf16_lo(qs.z), a5 = bf16_hi(qs.z);
        float a6 = bf16_lo(qs.w), a7 = bf16_hi(qs.w);

        const int* rp = rec + j0;
        int tt = 0;
        for (; tt + 8 <= deg; tt += 8) {
            int s[8]; uint4 q[8];
#pragma unroll
            for (int u = 0; u < 8; u++) s[u] = rp[tt + u];
#pragma unroll
            for (int u = 0; u < 8; u++) q[u] = h4[(size_t)s[u] * 8 + off];
#pragma unroll
            for (int u = 0; u < 8; u++) {
                a0 += bf16_lo(q[u].x); a1 += bf16_hi(q[u].x);
                a2 += bf16_lo(q[u].y); a3 += bf16_hi(q[u].y);
                a4 += bf16_lo(q[u].z); a5 += bf16_hi(q[u].z);
                a6 += bf16_lo(q[u].w); a7 += bf16_hi(q[u].w);
            }
        }
        for (; tt + 2 <= deg; tt += 2) {
            int s0i = rp[tt], s1i = rp[tt + 1];
            uint4 q0 = h4[(size_t)s0i * 8 + off];
            uint4 q1 = h4[(size_t)s1i * 8 + off];
            a0 += bf16_lo(q0.x) + bf16_lo(q1.x);
            a1 += bf16_hi(q0.x) + bf16_hi(q1.x);
            a2 += bf16_lo(q0.y) + bf16_lo(q1.y);
            a3 += bf16_hi(q0.y) + bf16_hi(q1.y);
            a4 += bf16_lo(q0.z) + bf16_lo(q1.z);
            a5 += bf16_hi(q0.z) + bf16_hi(q1.z);
            a6 += bf16_lo(q0.w) + bf16_lo(q1.w);
            a7 += bf16_hi(q0.w) + bf16_hi(q1.w);
        }
        if (tt < deg) {
            int s = rp[tt];
            uint4 q0 = h4[(size_t)s * 8 + off];
            a0 += bf16_lo(q0.x); a1 += bf16_hi(q0.x);
            a2 += bf16_lo(q0.y); a3 += bf16_hi(q0.y);
            a4 += bf16_lo(q0.z); a5 += bf16_hi(q0.z);
            a6 += bf16_lo(q0.w); a7 += bf16_hi(q0.w);
        }

        if (valid) {
            int fb = hf * 32 + 8 * fl;
            float4 bb0 = *(const float4*)&bias[fb];
            float4 bb1 = *(const float4*)&bias[fb + 4];
            float4 o0, o1;
            o0.x = di * a0 + bb0.x; o0.y = di * a1 + bb0.y;
            o0.z = di * a2 + bb0.z; o0.w = di * a3 + bb0.w;
            o1.x = di * a4 + bb1.x; o1.y = di * a5 + bb1.y;
            o1.z = di * a6 + bb1.z; o1.w = di * a7 + bb1.w;
            *(float4*)&out[(size_t)w * 64 + fb] = o0;
            *(float4*)&out[(size_t)w * 64 + fb + 4] = o1;
        }
    }
}

extern "C" void kernel_launch(void* const* d_in, const int* in_sizes, int n_in,
                              void* d_out, int out_size, void* d_ws, size_t ws_size,
                              hipStream_t stream) {
    const float* x = (const float*)d_in[0];
    const int* edge = (const int*)d_in[1];
    const float* W1 = (const float*)d_in[2];
    const float* b1 = (const float*)d_in[3];
    const float* W2 = (const float*)d_in[4];
    const float* b2 = (const float*)d_in[5];

    const int N = in_sizes[0] / 128;
    const int E = in_sizes[1] / 2;
    const int* src = edge;
    const int* dst = edge + E;
    const int NB = (N + (1 << BSH) - 1) >> BSH;   // coarse buckets (<= 512)

    // workspace carve-up (all chunks 16B-aligned for these sizes)
    char* p = (char*)d_ws;
    int* bcnt = (int*)p;      p += NBMAX * 4;
    int* bstart = (int*)p;    p += NBMAX * 4;
    int* bcursor = (int*)p;   p += NBMAX * 4;
    int* wcur = (int*)p;      p += 16;                  // [0,1]=agg128h, [2,3]=agg64h
    float* dinv = (float*)p;  p += (size_t)N * 4;
    int4* meta = (int4*)p;    p += (size_t)N * 16;      // (start, deg, dinv, dinv^2)
    int* rec = (int*)p;       p += (size_t)E * 4;       // src per edge (CSR by dst)
    uint* staged = (uint*)p;  p += (size_t)E * 4;       // packed (src<<8|dloc)
    uint* hq = (uint*)p;      p += (size_t)N * 64 * 4;  // dinv[r]*(x@W1), bf16
    uint* gq = (uint*)p;      p += (size_t)N * 64 * 4;  // relu layer-1 out, bf16
    uint* h2q = (uint*)p;     p += (size_t)N * 32 * 4;  // dinv[r]*h2, bf16 (64 feats)

    float* out = (float*)d_out;
    const int eblocks = (E + 2047) / 2048;

    // CSR build (two-level bucketed, zero per-node global atomics)
    (void)hipMemsetAsync(bcnt, 0, NBMAX * 4, stream);
    (void)hipMemsetAsync(wcur, 0, 16, stream);
    bucket_hist_kernel<<<eblocks, 256, 0, stream>>>(dst, bcnt, E, NB);
    bucket_scan<<<1, NBMAX, 0, stream>>>(bcnt, bstart, bcursor, NB);
    partition_kernel<<<eblocks, 256, 0, stream>>>(src, dst, bcursor, staged, E, NB);
    fine_csr_kernel<<<NB, 256, 0, stream>>>(staged, bstart, bcnt, meta, dinv, rec, N);

    const int gblocks = (N + 63) / 64;

    // layer 1 GEMM: hq = dinv .* (x @ W1) (bf16, pre-scaled rows)
    gemm_mfma<128, true><<<gblocks, 256, 0, stream>>>(x, W1, hq, dinv, N);
    // layer 1 aggregation (feature-split, XCD-affine): gq = relu(di*sum + b1)
    agg128h<<<1024, 512, 0, stream>>>(hq, rec, meta, b1, wcur, gq, N);
    // layer 2 GEMM: h2q = dinv .* (gq @ W2)
    gemm_mfma<64, false><<<gblocks, 256, 0, stream>>>(gq, W2, h2q, dinv, N);
    // layer 2 aggregation (feature-split, XCD-affine): out = di*sum + b2
    agg64h<<<1024, 512, 0, stream>>>(h2q, rec, meta, b2, wcur + 2, out, N);
}

// Round 6
// 351.610 us; speedup vs baseline: 1.2338x; 1.2338x over previous
//
#include <hip/hip_runtime.h>
#include <hip/hip_bf16.h>

// GCN 2-layer: h = relu(Anorm @ (x@W1) + b1); out = Anorm @ (h@W2) + b2
// R15 changes vs R14:
//  - REVERT feature-split/XCD-affinity (R14: FETCH 186->378MB, every edge
//    missed; per-XCD half-row set 12.6MB >> 4MB L2. The unsplit R12 kernel
//    already achieves per-XCD dedup: 186MB = 8 x N(1-e^-2) x 256B floor).
//  - Back to R12 structure (294us known-good) + ONE change: fine_csr now
//    SORTS each node's neighbor segment (rec) ascending. Gathers in both
//    agg kernels then issue monotonically increasing addresses -> better
//    DRAM/L2 sector behavior at identical byte count. (R11 showed the
//    fabric can deliver 3.57 TB/s; R12's agg runs at 2.84.)

#define NTHREADS 256
#define BSH 8                 // bucket = dst >> 8 (256 nodes/bucket)
#define NBMAX 512
#define FC_CAP 8192           // LDS edge cache per bucket

typedef unsigned int uint;
typedef unsigned short ushort;
typedef __attribute__((ext_vector_type(8))) short short8;
typedef __attribute__((ext_vector_type(4))) float floatx4;

__device__ __forceinline__ uint pack_bf16(float a, float b) {
    __hip_bfloat162 h = __float22bfloat162_rn(make_float2(a, b));
    return *reinterpret_cast<uint*>(&h);
}
__device__ __forceinline__ float bf16_lo(uint q) { return __uint_as_float(q << 16); }
__device__ __forceinline__ float bf16_hi(uint q) { return __uint_as_float(q & 0xffff0000u); }

// ---------- coarse bucket histogram only (no per-node atomics) ----------
__global__ __launch_bounds__(256) void bucket_hist_kernel(
    const int* __restrict__ dst, int* __restrict__ bcnt, int e, int nb) {
    __shared__ int hist[NBMAX];
    int t = threadIdx.x;
    for (int b = t; b < nb; b += 256) hist[b] = 0;
    __syncthreads();
    int e0 = blockIdx.x * 2048;
#pragma unroll
    for (int v = 0; v < 2; v++) {
        int gi = e0 + t * 8 + v * 4;
        if (gi + 3 < e) {
            int4 d4 = *(const int4*)&dst[gi];
            atomicAdd(&hist[d4.x >> BSH], 1);
            atomicAdd(&hist[d4.y >> BSH], 1);
            atomicAdd(&hist[d4.z >> BSH], 1);
            atomicAdd(&hist[d4.w >> BSH], 1);
        } else {
            for (int j = 0; j < 4; j++)
                if (gi + j < e) atomicAdd(&hist[dst[gi + j] >> BSH], 1);
        }
    }
    __syncthreads();
    for (int b = t; b < nb; b += 256) {
        int v = hist[b];
        if (v) atomicAdd(&bcnt[b], v);
    }
}

// ---------- bucket scan (nb <= 512, single block of 512) ----------
__global__ void bucket_scan(const int* __restrict__ bcnt, int* __restrict__ bstart,
                            int* __restrict__ bcursor, int nb) {
    __shared__ int buf[NBMAX];
    int t = threadIdx.x;
    int v = (t < nb) ? bcnt[t] : 0;
    buf[t] = v;
    __syncthreads();
    int x = v;
    for (int off = 1; off < NBMAX; off <<= 1) {
        int y = (t >= off) ? buf[t - off] : 0;
        __syncthreads();
        x += y;
        buf[t] = x;
        __syncthreads();
    }
    if (t < nb) {
        bstart[t] = x - v;
        bcursor[t] = x - v;
    }
}

// ---------- coarse partition: staged[] = packed (src<<8|dloc) by bucket ----------
__global__ __launch_bounds__(256) void partition_kernel(
    const int* __restrict__ src, const int* __restrict__ dst,
    int* __restrict__ bcursor, uint* __restrict__ staged, int e, int nb) {
    __shared__ uint eP[2048];        // packed (src<<8 | dst&255)
    __shared__ ushort eB[2048];      // bucket id (0xFFFF = invalid)
    __shared__ int hist[NBMAX];
    __shared__ int base[NBMAX];
    int t = threadIdx.x;
    int e0 = blockIdx.x * 2048;

    for (int b = t; b < nb; b += 256) hist[b] = 0;
    __syncthreads();
#pragma unroll
    for (int v = 0; v < 2; v++) {
        int li = t * 8 + v * 4;
        int gi = e0 + li;
        int4 s4, d4;
        if (gi + 3 < e) {
            s4 = *(const int4*)&src[gi];
            d4 = *(const int4*)&dst[gi];
        } else {
            const int* sp = &src[gi];
            const int* dp = &dst[gi];
            s4.x = (gi + 0 < e) ? sp[0] : 0;  d4.x = (gi + 0 < e) ? dp[0] : -1;
            s4.y = (gi + 1 < e) ? sp[1] : 0;  d4.y = (gi + 1 < e) ? dp[1] : -1;
            s4.z = (gi + 2 < e) ? sp[2] : 0;  d4.z = (gi + 2 < e) ? dp[2] : -1;
            s4.w = (gi + 3 < e) ? sp[3] : 0;  d4.w = (gi + 3 < e) ? dp[3] : -1;
        }
        uint4 p4;
        p4.x = ((uint)s4.x << 8) | ((uint)d4.x & 255u);
        p4.y = ((uint)s4.y << 8) | ((uint)d4.y & 255u);
        p4.z = ((uint)s4.z << 8) | ((uint)d4.z & 255u);
        p4.w = ((uint)s4.w << 8) | ((uint)d4.w & 255u);
        *(uint4*)&eP[li] = p4;
        eB[li + 0] = (d4.x >= 0) ? (ushort)(d4.x >> BSH) : (ushort)0xFFFF;
        eB[li + 1] = (d4.y >= 0) ? (ushort)(d4.y >> BSH) : (ushort)0xFFFF;
        eB[li + 2] = (d4.z >= 0) ? (ushort)(d4.z >> BSH) : (ushort)0xFFFF;
        eB[li + 3] = (d4.w >= 0) ? (ushort)(d4.w >> BSH) : (ushort)0xFFFF;
        if (d4.x >= 0) atomicAdd(&hist[d4.x >> BSH], 1);
        if (d4.y >= 0) atomicAdd(&hist[d4.y >> BSH], 1);
        if (d4.z >= 0) atomicAdd(&hist[d4.z >> BSH], 1);
        if (d4.w >= 0) atomicAdd(&hist[d4.w >> BSH], 1);
    }
    __syncthreads();
    for (int b = t; b < nb; b += 256) {
        int v = hist[b];
        base[b] = v ? atomicAdd(&bcursor[b], v) : 0;
        hist[b] = 0;   // reset for rank pass
    }
    __syncthreads();
#pragma unroll
    for (int i = 0; i < 8; i++) {
        int li = t + i * 256;
        ushort bb = eB[li];
        if (bb != (ushort)0xFFFF) {
            int r = atomicAdd(&hist[bb], 1);
            staged[base[bb] + r] = eP[li];
        }
    }
}

// ---------- per-bucket fused CSR: count+scan -> meta/dinv, LDS-cached fill,
//            then per-node ascending sort of the neighbor segment ----------
__global__ __launch_bounds__(256) void fine_csr_kernel(
    const uint* __restrict__ staged, const int* __restrict__ bstart,
    const int* __restrict__ bcnt, int4* __restrict__ meta,
    float* __restrict__ dinv, int* __restrict__ rec, int n) {
    __shared__ uint eL[FC_CAP];      // 32 KB edge cache (reused as sort scratch)
    __shared__ int lcnt[256];
    __shared__ int tsum[256];
    int b = blockIdx.x;
    int t = threadIdx.x;
    lcnt[t] = 0;
    __syncthreads();
    int s0 = bstart[b];
    int m = bcnt[b];
    for (int i = t; i < m; i += 256) {
        uint pk = staged[s0 + i];
        if (i < FC_CAP) eL[i] = pk;
        atomicAdd(&lcnt[pk & 255u], 1);
    }
    __syncthreads();
    int v = lcnt[t];
    tsum[t] = v;
    __syncthreads();
    int x = v;
    for (int off = 1; off < 256; off <<= 1) {
        int y = (t >= off) ? tsum[t - off] : 0;
        __syncthreads();
        x += y;
        tsum[t] = x;
        __syncthreads();
    }
    int excl = x - v;
    int node = (b << BSH) + t;
    if (node < n) {
        float di = rsqrtf((float)v + 1.0f);
        dinv[node] = di;
        meta[node] = make_int4(s0 + excl, v, __float_as_int(di), __float_as_int(di * di));
    }
    lcnt[t] = s0 + excl;             // repurpose as absolute cursor
    __syncthreads();
    // fill: rec[pos] = src (edges come from LDS cache)
    for (int i = t; i < m; i += 256) {
        uint pk = (i < FC_CAP) ? eL[i] : staged[s0 + i];
        int pos = atomicAdd(&lcnt[pk & 255u], 1);
        rec[pos] = (int)(pk >> 8);
    }
    __syncthreads();   // drains this block's rec stores (vmcnt(0) before barrier)
    // sort node t's segment ascending (perf hint for the gather kernels;
    // segments longer than 32 are left unsorted — correctness unaffected).
    // eL is free now: 8192 slots / 256 threads = 32 slots each.
    if (node < n && v > 1 && v <= 32) {
        uint* my = &eL[t * 32];
        int base = s0 + excl;
        for (int i = 0; i < v; i++) my[i] = (uint)rec[base + i];
        for (int i = 1; i < v; i++) {
            uint key = my[i];
            int j = i - 1;
            while (j >= 0 && my[j] > key) { my[j + 1] = my[j]; j--; }
            my[j + 1] = key;
        }
        for (int i = 0; i < v; i++) rec[base + i] = (int)my[i];
    }
}

// ---------- bf16 MFMA GEMM: Cq[n,COLS](bf16) = dscale[r] * (X[n,128] @ W[128,COLS]) ----------
template <int COLS, bool XF32>
__global__ __launch_bounds__(256) void gemm_mfma(const void* __restrict__ Xv,
                                                 const float* __restrict__ W,
                                                 uint* __restrict__ Cq,
                                                 const float* __restrict__ dscale,
                                                 int n) {
    __shared__ ushort sX[64 * 128];
    __shared__ ushort sWT[COLS * 128];
    int t = threadIdx.x;
    int rbase = blockIdx.x * 64;

    if (XF32) {
        const float* X = (const float*)Xv;
#pragma unroll
        for (int i = 0; i < 8; i++) {
            int f = t + 256 * i;
            int r = f >> 5;
            int c4 = f & 31;
            float4 v = make_float4(0.f, 0.f, 0.f, 0.f);
            int gr = rbase + r;
            if (gr < n) v = *(const float4*)(X + (size_t)gr * 128 + c4 * 4);
            uint lo = pack_bf16(v.x, v.y);
            uint hi = pack_bf16(v.z, v.w);
            int chunk = c4 >> 1;
            int sub = (c4 & 1) * 4;
            int off = r * 128 + (((chunk ^ (r & 15)) << 3) + sub);
            *(uint2*)&sX[off] = make_uint2(lo, hi);
        }
    } else {
        const ushort* X = (const ushort*)Xv;
#pragma unroll
        for (int i = 0; i < 4; i++) {
            int f = t + 256 * i;
            int r = f >> 4;
            int chunk = f & 15;
            uint4 v = make_uint4(0, 0, 0, 0);
            int gr = rbase + r;
            if (gr < n) v = *(const uint4*)(X + (size_t)gr * 128 + chunk * 8);
            int off = r * 128 + ((chunk ^ (r & 15)) << 3);
            *(uint4*)&sX[off] = v;
        }
    }
    {
        constexpr int UNITS = 64 * (COLS / 4);
        constexpr int PER_T = UNITS / 256;
#pragma unroll
        for (int i = 0; i < PER_T; i++) {
            int u = t + 256 * i;
            int kp = u / (COLS / 4);
            int n4 = u % (COLS / 4);
            int k = kp * 2;
            float4 w0 = *(const float4*)(W + (size_t)k * COLS + n4 * 4);
            float4 w1 = *(const float4*)(W + (size_t)(k + 1) * COLS + n4 * 4);
            int chunk = k >> 3;
            int sub = k & 7;
            const float* a0 = (const float*)&w0;
            const float* a1 = (const float*)&w1;
#pragma unroll
            for (int j = 0; j < 4; j++) {
                int nn = n4 * 4 + j;
                uint pk = pack_bf16(a0[j], a1[j]);
                int off = nn * 128 + (((chunk ^ (nn & 15)) << 3) + sub);
                *(uint*)&sWT[off] = pk;
            }
        }
    }
    __syncthreads();

    int lane = t & 63;
    int wave = t >> 6;
    int m = lane & 15;
    int q = lane >> 4;
    int r0 = wave * 16;

    floatx4 acc[COLS / 16];
#pragma unroll
    for (int c = 0; c < COLS / 16; c++) acc[c] = (floatx4){0.f, 0.f, 0.f, 0.f};

#pragma unroll
    for (int ks = 0; ks < 4; ks++) {
        int rr = r0 + m;
        int ca = (ks * 4 + q) ^ (rr & 15);
        short8 afrag = *(const short8*)&sX[rr * 128 + (ca << 3)];
#pragma unroll
        for (int c = 0; c < COLS / 16; c++) {
            int nn = c * 16 + m;
            int cb = (ks * 4 + q) ^ (nn & 15);
            short8 bfrag = *(const short8*)&sWT[nn * 128 + (cb << 3)];
            acc[c] = __builtin_amdgcn_mfma_f32_16x16x32_bf16(bfrag, afrag, acc[c], 0, 0, 0);
        }
    }

    int gr = rbase + r0 + m;
    if (gr < n) {
        float sc = dscale[gr];
#pragma unroll
        for (int c = 0; c < COLS / 16; c++) {
            uint2 pk;
            pk.x = pack_bf16(acc[c][0] * sc, acc[c][1] * sc);
            pk.y = pack_bf16(acc[c][2] * sc, acc[c][3] * sc);
            *(uint2*)&Cq[(size_t)gr * (COLS / 2) + c * 8 + q * 2] = pk;
        }
    }
}

// ---------- FUSED: aggregate layer-1 (D=128) + GEMM2 (128->64) ----------
// 512 threads = 32 quarter-waves = 32 nodes/block (R10/R12 form, proven).
__global__ __launch_bounds__(512) void agg128_mm64(
    const uint* __restrict__ hq, const int* __restrict__ rec,
    const int4* __restrict__ meta, const float* __restrict__ dinv,
    const float* __restrict__ bias, const float* __restrict__ W2,
    uint* __restrict__ h2q, int n) {
    __shared__ ushort sWT[64 * 128];   // 16 KB
    __shared__ ushort sg[32 * 128];    // 8 KB
    int t = threadIdx.x;

    // stage W2^T (f32 -> bf16, XOR swizzle) — same pattern as gemm_mfma<64>
#pragma unroll
    for (int i = 0; i < 2; i++) {
        int u = t + 512 * i;          // 0..1023 = (kp, n4)
        int kp = u >> 4;
        int n4 = u & 15;
        int k = kp * 2;
        float4 w0 = *(const float4*)(W2 + (size_t)k * 64 + n4 * 4);
        float4 w1 = *(const float4*)(W2 + (size_t)(k + 1) * 64 + n4 * 4);
        int chunk = k >> 3;
        int sub = k & 7;
        const float* a0f = (const float*)&w0;
        const float* a1f = (const float*)&w1;
#pragma unroll
        for (int j = 0; j < 4; j++) {
            int nn = n4 * 4 + j;
            uint pk = pack_bf16(a0f[j], a1f[j]);
            *(uint*)&sWT[nn * 128 + (((chunk ^ (nn & 15)) << 3) + sub)] = pk;
        }
    }

    int qw = t >> 4;                  // 0..31 local node
    int fl = t & 15;                  // uint4 lane: features 8*fl .. 8*fl+7
    int nb0 = blockIdx.x * 32;
    int w = nb0 + qw;
    bool valid = w < n;
    int wsafe = valid ? w : 0;
    const uint4* h4 = (const uint4*)hq;   // row = 16 uint4

    int4 mt = meta[wsafe];
    int j0 = mt.x;
    int deg = valid ? mt.y : 0;
    float di = __int_as_float(mt.z);

    // self term (pre-scaled row, weight 1)
    uint4 qs = h4[(size_t)wsafe * 16 + fl];
    float a0 = bf16_lo(qs.x), a1 = bf16_hi(qs.x);
    float a2 = bf16_lo(qs.y), a3 = bf16_hi(qs.y);
    float a4 = bf16_lo(qs.z), a5 = bf16_hi(qs.z);
    float a6 = bf16_lo(qs.w), a7 = bf16_hi(qs.w);
    if (!valid) { a0 = a1 = a2 = a3 = a4 = a5 = a6 = a7 = 0.f; }

    const int* rp = rec + j0;
    int tt = 0;
    for (; tt + 8 <= deg; tt += 8) {
        int s[8]; uint4 q[8];
#pragma unroll
        for (int u = 0; u < 8; u++) s[u] = rp[tt + u];
#pragma unroll
        for (int u = 0; u < 8; u++) q[u] = h4[(size_t)s[u] * 16 + fl];
#pragma unroll
        for (int u = 0; u < 8; u++) {
            a0 += bf16_lo(q[u].x); a1 += bf16_hi(q[u].x);
            a2 += bf16_lo(q[u].y); a3 += bf16_hi(q[u].y);
            a4 += bf16_lo(q[u].z); a5 += bf16_hi(q[u].z);
            a6 += bf16_lo(q[u].w); a7 += bf16_hi(q[u].w);
        }
    }
    for (; tt + 2 <= deg; tt += 2) {
        int s0i = rp[tt], s1i = rp[tt + 1];
        uint4 q0 = h4[(size_t)s0i * 16 + fl];
        uint4 q1 = h4[(size_t)s1i * 16 + fl];
        a0 += bf16_lo(q0.x) + bf16_lo(q1.x);
        a1 += bf16_hi(q0.x) + bf16_hi(q1.x);
        a2 += bf16_lo(q0.y) + bf16_lo(q1.y);
        a3 += bf16_hi(q0.y) + bf16_hi(q1.y);
        a4 += bf16_lo(q0.z) + bf16_lo(q1.z);
        a5 += bf16_hi(q0.z) + bf16_hi(q1.z);
        a6 += bf16_lo(q0.w) + bf16_lo(q1.w);
        a7 += bf16_hi(q0.w) + bf16_hi(q1.w);
    }
    if (tt < deg) {
        int s = rp[tt];
        uint4 q0 = h4[(size_t)s * 16 + fl];
        a0 += bf16_lo(q0.x); a1 += bf16_hi(q0.x);
        a2 += bf16_lo(q0.y); a3 += bf16_hi(q0.y);
        a4 += bf16_lo(q0.z); a5 += bf16_hi(q0.z);
        a6 += bf16_lo(q0.w); a7 += bf16_hi(q0.w);
    }

    // g = relu(di*acc + b1) -> bf16 -> LDS (same swizzle as gemm_mfma staging)
    float4 bb0 = *(const float4*)&bias[8 * fl];
    float4 bb1 = *(const float4*)&bias[8 * fl + 4];
    uint4 pkv;
    pkv.x = pack_bf16(fmaxf(di * a0 + bb0.x, 0.f), fmaxf(di * a1 + bb0.y, 0.f));
    pkv.y = pack_bf16(fmaxf(di * a2 + bb0.z, 0.f), fmaxf(di * a3 + bb0.w, 0.f));
    pkv.z = pack_bf16(fmaxf(di * a4 + bb1.x, 0.f), fmaxf(di * a5 + bb1.y, 0.f));
    pkv.w = pack_bf16(fmaxf(di * a6 + bb1.z, 0.f), fmaxf(di * a7 + bb1.w, 0.f));
    *(uint4*)&sg[qw * 128 + ((fl ^ (qw & 15)) << 3)] = pkv;
    __syncthreads();

    // h2 = g @ W2 : 32 rows x 64 cols, 8 waves = 2 row-tiles x 4 col-tiles
    int wave = t >> 6;
    int lane = t & 63;
    int m = lane & 15;
    int qq = lane >> 4;
    int rt = wave >> 2;               // row tile 0..1
    int ct = wave & 3;                // col tile 0..3
    floatx4 acc = (floatx4){0.f, 0.f, 0.f, 0.f};
#pragma unroll
    for (int ks = 0; ks < 4; ks++) {
        int rr = rt * 16 + m;
        int ca = (ks * 4 + qq) ^ (rr & 15);
        short8 afrag = *(const short8*)&sg[rr * 128 + (ca << 3)];
        int nn = ct * 16 + m;
        int cb = (ks * 4 + qq) ^ (nn & 15);
        short8 bfrag = *(const short8*)&sWT[nn * 128 + (cb << 3)];
        acc = __builtin_amdgcn_mfma_f32_16x16x32_bf16(bfrag, afrag, acc, 0, 0, 0);
    }
    int gr = nb0 + rt * 16 + m;
    if (gr < n) {
        float sc = dinv[gr];          // pre-scale h2 rows for layer-2 gather
        uint2 pk;
        pk.x = pack_bf16(acc[0] * sc, acc[1] * sc);
        pk.y = pack_bf16(acc[2] * sc, acc[3] * sc);
        *(uint2*)&h2q[(size_t)gr * 32 + ct * 8 + qq * 2] = pk;
    }
}

// ---------- pull aggregation, D=64 (pre-scaled bf16 in, f32 out) ----------
// eighth-wave: 8 lanes x uint4 = 128B row (R10/R12 form, proven).
__global__ __launch_bounds__(256) void aggregate64q(
    const uint* __restrict__ hq, const int* __restrict__ rec,
    const int4* __restrict__ meta, const float* __restrict__ bias,
    float* __restrict__ out, int n) {
    int gt = blockIdx.x * 256 + threadIdx.x;
    int w = gt >> 3;
    if (w >= n) return;
    int fl = gt & 7;                  // features 8*fl .. 8*fl+7

    int4 mt = meta[w];
    int j0 = mt.x;
    int deg = mt.y;
    float di = __int_as_float(mt.z);
    const uint4* h4 = (const uint4*)hq;   // row = 8 uint4

    uint4 qs = h4[(size_t)w * 8 + fl];
    float a0 = bf16_lo(qs.x), a1 = bf16_hi(qs.x);
    float a2 = bf16_lo(qs.y), a3 = bf16_hi(qs.y);
    float a4 = bf16_lo(qs.z), a5 = bf16_hi(qs.z);
    float a6 = bf16_lo(qs.w), a7 = bf16_hi(qs.w);

    const int* rp = rec + j0;
    int tt = 0;
    for (; tt + 8 <= deg; tt += 8) {
        int s[8]; uint4 q[8];
#pragma unroll
        for (int u = 0; u < 8; u++) s[u] = rp[tt + u];
#pragma unroll
        for (int u = 0; u < 8; u++) q[u] = h4[(size_t)s[u] * 8 + fl];
#pragma unroll
        for (int u = 0; u < 8; u++) {
            a0 += bf16_lo(q[u].x); a1 += bf16_hi(q[u].x);
            a2 += bf16_lo(q[u].y); a3 += bf16_hi(q[u].y);
            a4 += bf16_lo(q[u].z); a5 += bf16_hi(q[u].z);
            a6 += bf16_lo(q[u].w); a7 += bf16_hi(q[u].w);
        }
    }
    for (; tt + 2 <= deg; tt += 2) {
        int s0i = rp[tt], s1i = rp[tt + 1];
        uint4 q0 = h4[(size_t)s0i * 8 + fl];
        uint4 q1 = h4[(size_t)s1i * 8 + fl];
        a0 += bf16_lo(q0.x) + bf16_lo(q1.x);
        a1 += bf16_hi(q0.x) + bf16_hi(q1.x);
        a2 += bf16_lo(q0.y) + bf16_lo(q1.y);
        a3 += bf16_hi(q0.y) + bf16_hi(q1.y);
        a4 += bf16_lo(q0.z) + bf16_lo(q1.z);
        a5 += bf16_hi(q0.z) + bf16_hi(q1.z);
        a6 += bf16_lo(q0.w) + bf16_lo(q1.w);
        a7 += bf16_hi(q0.w) + bf16_hi(q1.w);
    }
    if (tt < deg) {
        int s = rp[tt];
        uint4 q0 = h4[(size_t)s * 8 + fl];
        a0 += bf16_lo(q0.x); a1 += bf16_hi(q0.x);
        a2 += bf16_lo(q0.y); a3 += bf16_hi(q0.y);
        a4 += bf16_lo(q0.z); a5 += bf16_hi(q0.z);
        a6 += bf16_lo(q0.w); a7 += bf16_hi(q0.w);
    }

    float4 bb0 = *(const float4*)&bias[8 * fl];
    float4 bb1 = *(const float4*)&bias[8 * fl + 4];
    float4 o0, o1;
    o0.x = di * a0 + bb0.x; o0.y = di * a1 + bb0.y;
    o0.z = di * a2 + bb0.z; o0.w = di * a3 + bb0.w;
    o1.x = di * a4 + bb1.x; o1.y = di * a5 + bb1.y;
    o1.z = di * a6 + bb1.z; o1.w = di * a7 + bb1.w;
    *(float4*)&out[(size_t)w * 64 + 8 * fl] = o0;
    *(float4*)&out[(size_t)w * 64 + 8 * fl + 4] = o1;
}

extern "C" void kernel_launch(void* const* d_in, const int* in_sizes, int n_in,
                              void* d_out, int out_size, void* d_ws, size_t ws_size,
                              hipStream_t stream) {
    const float* x = (const float*)d_in[0];
    const int* edge = (const int*)d_in[1];
    const float* W1 = (const float*)d_in[2];
    const float* b1 = (const float*)d_in[3];
    const float* W2 = (const float*)d_in[4];
    const float* b2 = (const float*)d_in[5];

    const int N = in_sizes[0] / 128;
    const int E = in_sizes[1] / 2;
    const int* src = edge;
    const int* dst = edge + E;
    const int NB = (N + (1 << BSH) - 1) >> BSH;   // coarse buckets (<= 512)

    // workspace carve-up (all chunks 16B-aligned for these sizes)
    char* p = (char*)d_ws;
    int* bcnt = (int*)p;      p += NBMAX * 4;
    int* bstart = (int*)p;    p += NBMAX * 4;
    int* bcursor = (int*)p;   p += NBMAX * 4;
    float* dinv = (float*)p;  p += (size_t)N * 4;
    int4* meta = (int4*)p;    p += (size_t)N * 16;      // (start, deg, dinv, dinv^2)
    int* rec = (int*)p;       p += (size_t)E * 4;       // src per edge (CSR by dst, sorted)
    uint* staged = (uint*)p;  p += (size_t)E * 4;       // packed (src<<8|dloc)
    uint* hq = (uint*)p;      p += (size_t)N * 64 * 4;  // dinv[r]*(x@W1), bf16 pairs
    uint* h2q = (uint*)p;     p += (size_t)N * 32 * 4;  // dinv[r]*h2, bf16 (64 feats)

    float* out = (float*)d_out;
    const int eblocks = (E + 2047) / 2048;

    // CSR build (two-level bucketed, zero per-node global atomics)
    (void)hipMemsetAsync(bcnt, 0, NBMAX * 4, stream);
    bucket_hist_kernel<<<eblocks, 256, 0, stream>>>(dst, bcnt, E, NB);
    bucket_scan<<<1, NBMAX, 0, stream>>>(bcnt, bstart, bcursor, NB);
    partition_kernel<<<eblocks, 256, 0, stream>>>(src, dst, bcursor, staged, E, NB);
    fine_csr_kernel<<<NB, 256, 0, stream>>>(staged, bstart, bcnt, meta, dinv, rec, N);

    const int gblocks = (N + 63) / 64;

    // layer 1 GEMM: hq = dinv .* (x @ W1) (bf16, pre-scaled rows)
    gemm_mfma<128, true><<<gblocks, 256, 0, stream>>>(x, W1, hq, dinv, N);
    // fused: g = relu(di*(sum of pre-scaled rows) + b1); h2q = dinv .* (g @ W2)
    agg128_mm64<<<(N + 31) / 32, 512, 0, stream>>>(hq, rec, meta, dinv, b1, W2, h2q, N);
    // layer 2 aggregation: out = di*(sum of pre-scaled h2 rows) + b2
    aggregate64q<<<(N * 8 + 255) / 256, 256, 0, stream>>>(h2q, rec, meta, b2, out, N);
}

// Round 7
// 274.890 us; speedup vs baseline: 1.5781x; 1.2791x over previous
//
#include <hip/hip_runtime.h>
#include <hip/hip_bf16.h>

// GCN 2-layer: h = relu(Anorm @ (x@W1) + b1); out = Anorm @ (h@W2) + b2
// R16 changes vs R15:
//  - REVERT neighbor-sort (R15: +55us in fine_csr from 32-way LDS bank
//    conflicts + serial rec rewrite; zero gain in the gathers -> gather
//    is at its structural floor, question closed).
//  - KILL bucket_hist + bucket_scan dispatches: staged[] becomes fixed-
//    capacity bucket regions [NB][CAP=5632] (counts ~Poisson(4096),
//    CAP=+24sigma). partition claims slots via b*CAP + atomicAdd(bfill).
//    fine_csr computes its dense rec offset by reducing bfill[0..b-1]
//    in-block (~391 adds). Dispatch chain 8 -> 6; src/dst read once.
//  - agg128_mm64 / aggregate64q / gemm_mfma: R12 proven forms, untouched.

#define NTHREADS 256
#define BSH 8                 // bucket = dst >> 8 (256 nodes/bucket)
#define NBMAX 512
#define BCAP 5632             // fixed slots per bucket (mean 4096, +24 sigma)
#define FC_CAP 8192           // LDS edge cache per bucket

typedef unsigned int uint;
typedef unsigned short ushort;
typedef __attribute__((ext_vector_type(8))) short short8;
typedef __attribute__((ext_vector_type(4))) float floatx4;

__device__ __forceinline__ uint pack_bf16(float a, float b) {
    __hip_bfloat162 h = __float22bfloat162_rn(make_float2(a, b));
    return *reinterpret_cast<uint*>(&h);
}
__device__ __forceinline__ float bf16_lo(uint q) { return __uint_as_float(q << 16); }
__device__ __forceinline__ float bf16_hi(uint q) { return __uint_as_float(q & 0xffff0000u); }

// ---------- single-pass partition into fixed-capacity bucket regions ----------
// staged[b*BCAP + r] = packed (src<<8 | dst&255); bfill[b] = bucket count.
__global__ __launch_bounds__(256) void partition_kernel(
    const int* __restrict__ src, const int* __restrict__ dst,
    int* __restrict__ bfill, uint* __restrict__ staged, int e, int nb) {
    __shared__ uint eP[2048];        // packed (src<<8 | dst&255)
    __shared__ ushort eB[2048];      // bucket id (0xFFFF = invalid)
    __shared__ int hist[NBMAX];
    __shared__ int base[NBMAX];
    int t = threadIdx.x;
    int e0 = blockIdx.x * 2048;

    for (int b = t; b < nb; b += 256) hist[b] = 0;
    __syncthreads();
#pragma unroll
    for (int v = 0; v < 2; v++) {
        int li = t * 8 + v * 4;
        int gi = e0 + li;
        int4 s4, d4;
        if (gi + 3 < e) {
            s4 = *(const int4*)&src[gi];
            d4 = *(const int4*)&dst[gi];
        } else {
            const int* sp = &src[gi];
            const int* dp = &dst[gi];
            s4.x = (gi + 0 < e) ? sp[0] : 0;  d4.x = (gi + 0 < e) ? dp[0] : -1;
            s4.y = (gi + 1 < e) ? sp[1] : 0;  d4.y = (gi + 1 < e) ? dp[1] : -1;
            s4.z = (gi + 2 < e) ? sp[2] : 0;  d4.z = (gi + 2 < e) ? dp[2] : -1;
            s4.w = (gi + 3 < e) ? sp[3] : 0;  d4.w = (gi + 3 < e) ? dp[3] : -1;
        }
        uint4 p4;
        p4.x = ((uint)s4.x << 8) | ((uint)d4.x & 255u);
        p4.y = ((uint)s4.y << 8) | ((uint)d4.y & 255u);
        p4.z = ((uint)s4.z << 8) | ((uint)d4.z & 255u);
        p4.w = ((uint)s4.w << 8) | ((uint)d4.w & 255u);
        *(uint4*)&eP[li] = p4;
        eB[li + 0] = (d4.x >= 0) ? (ushort)(d4.x >> BSH) : (ushort)0xFFFF;
        eB[li + 1] = (d4.y >= 0) ? (ushort)(d4.y >> BSH) : (ushort)0xFFFF;
        eB[li + 2] = (d4.z >= 0) ? (ushort)(d4.z >> BSH) : (ushort)0xFFFF;
        eB[li + 3] = (d4.w >= 0) ? (ushort)(d4.w >> BSH) : (ushort)0xFFFF;
        if (d4.x >= 0) atomicAdd(&hist[d4.x >> BSH], 1);
        if (d4.y >= 0) atomicAdd(&hist[d4.y >> BSH], 1);
        if (d4.z >= 0) atomicAdd(&hist[d4.z >> BSH], 1);
        if (d4.w >= 0) atomicAdd(&hist[d4.w >> BSH], 1);
    }
    __syncthreads();
    for (int b = t; b < nb; b += 256) {
        int v = hist[b];
        base[b] = v ? (b * BCAP + atomicAdd(&bfill[b], v)) : 0;
        hist[b] = 0;   // reset for rank pass
    }
    __syncthreads();
#pragma unroll
    for (int i = 0; i < 8; i++) {
        int li = t + i * 256;
        ushort bb = eB[li];
        if (bb != (ushort)0xFFFF) {
            int r = atomicAdd(&hist[bb], 1);
            staged[base[bb] + r] = eP[li];
        }
    }
}

// ---------- per-bucket fused CSR: dense offset by bfill reduction,
//            count+scan -> meta/dinv, LDS-cached fill ----------
__global__ __launch_bounds__(256) void fine_csr_kernel(
    const uint* __restrict__ staged, const int* __restrict__ bfill,
    int4* __restrict__ meta, float* __restrict__ dinv,
    int* __restrict__ rec, int n) {
    __shared__ uint eL[FC_CAP];      // 32 KB edge cache
    __shared__ int lcnt[256];
    __shared__ int tsum[256];
    __shared__ int red[256];
    int b = blockIdx.x;
    int t = threadIdx.x;

    // s0 = dense start = sum_{j<b} bfill[j]  (all blocks compute their own)
    int part = 0;
    for (int j = t; j < b; j += 256) part += bfill[j];
    red[t] = part;
    lcnt[t] = 0;
    __syncthreads();
    for (int off = 128; off > 0; off >>= 1) {
        if (t < off) red[t] += red[t + off];
        __syncthreads();
    }
    int s0 = red[0];
    int m = bfill[b];

    int sb = b * BCAP;               // sparse (staged) base for this bucket
    for (int i = t; i < m; i += 256) {
        uint pk = staged[sb + i];
        eL[i] = pk;                  // m <= BCAP < FC_CAP always
        atomicAdd(&lcnt[pk & 255u], 1);
    }
    __syncthreads();
    int v = lcnt[t];
    tsum[t] = v;
    __syncthreads();
    int x = v;
    for (int off = 1; off < 256; off <<= 1) {
        int y = (t >= off) ? tsum[t - off] : 0;
        __syncthreads();
        x += y;
        tsum[t] = x;
        __syncthreads();
    }
    int excl = x - v;
    int node = (b << BSH) + t;
    if (node < n) {
        float di = rsqrtf((float)v + 1.0f);
        dinv[node] = di;
        meta[node] = make_int4(s0 + excl, v, __float_as_int(di), __float_as_int(di * di));
    }
    lcnt[t] = s0 + excl;             // repurpose as absolute cursor
    __syncthreads();
    // fill: rec[pos] = src (edges come from LDS cache)
    for (int i = t; i < m; i += 256) {
        uint pk = eL[i];
        int pos = atomicAdd(&lcnt[pk & 255u], 1);
        rec[pos] = (int)(pk >> 8);
    }
}

// ---------- bf16 MFMA GEMM: Cq[n,COLS](bf16) = dscale[r] * (X[n,128] @ W[128,COLS]) ----------
template <int COLS, bool XF32>
__global__ __launch_bounds__(256) void gemm_mfma(const void* __restrict__ Xv,
                                                 const float* __restrict__ W,
                                                 uint* __restrict__ Cq,
                                                 const float* __restrict__ dscale,
                                                 int n) {
    __shared__ ushort sX[64 * 128];
    __shared__ ushort sWT[COLS * 128];
    int t = threadIdx.x;
    int rbase = blockIdx.x * 64;

    if (XF32) {
        const float* X = (const float*)Xv;
#pragma unroll
        for (int i = 0; i < 8; i++) {
            int f = t + 256 * i;
            int r = f >> 5;
            int c4 = f & 31;
            float4 v = make_float4(0.f, 0.f, 0.f, 0.f);
            int gr = rbase + r;
            if (gr < n) v = *(const float4*)(X + (size_t)gr * 128 + c4 * 4);
            uint lo = pack_bf16(v.x, v.y);
            uint hi = pack_bf16(v.z, v.w);
            int chunk = c4 >> 1;
            int sub = (c4 & 1) * 4;
            int off = r * 128 + (((chunk ^ (r & 15)) << 3) + sub);
            *(uint2*)&sX[off] = make_uint2(lo, hi);
        }
    } else {
        const ushort* X = (const ushort*)Xv;
#pragma unroll
        for (int i = 0; i < 4; i++) {
            int f = t + 256 * i;
            int r = f >> 4;
            int chunk = f & 15;
            uint4 v = make_uint4(0, 0, 0, 0);
            int gr = rbase + r;
            if (gr < n) v = *(const uint4*)(X + (size_t)gr * 128 + chunk * 8);
            int off = r * 128 + ((chunk ^ (r & 15)) << 3);
            *(uint4*)&sX[off] = v;
        }
    }
    {
        constexpr int UNITS = 64 * (COLS / 4);
        constexpr int PER_T = UNITS / 256;
#pragma unroll
        for (int i = 0; i < PER_T; i++) {
            int u = t + 256 * i;
            int kp = u / (COLS / 4);
            int n4 = u % (COLS / 4);
            int k = kp * 2;
            float4 w0 = *(const float4*)(W + (size_t)k * COLS + n4 * 4);
            float4 w1 = *(const float4*)(W + (size_t)(k + 1) * COLS + n4 * 4);
            int chunk = k >> 3;
            int sub = k & 7;
            const float* a0 = (const float*)&w0;
            const float* a1 = (const float*)&w1;
#pragma unroll
            for (int j = 0; j < 4; j++) {
                int nn = n4 * 4 + j;
                uint pk = pack_bf16(a0[j], a1[j]);
                int off = nn * 128 + (((chunk ^ (nn & 15)) << 3) + sub);
                *(uint*)&sWT[off] = pk;
            }
        }
    }
    __syncthreads();

    int lane = t & 63;
    int wave = t >> 6;
    int m = lane & 15;
    int q = lane >> 4;
    int r0 = wave * 16;

    floatx4 acc[COLS / 16];
#pragma unroll
    for (int c = 0; c < COLS / 16; c++) acc[c] = (floatx4){0.f, 0.f, 0.f, 0.f};

#pragma unroll
    for (int ks = 0; ks < 4; ks++) {
        int rr = r0 + m;
        int ca = (ks * 4 + q) ^ (rr & 15);
        short8 afrag = *(const short8*)&sX[rr * 128 + (ca << 3)];
#pragma unroll
        for (int c = 0; c < COLS / 16; c++) {
            int nn = c * 16 + m;
            int cb = (ks * 4 + q) ^ (nn & 15);
            short8 bfrag = *(const short8*)&sWT[nn * 128 + (cb << 3)];
            acc[c] = __builtin_amdgcn_mfma_f32_16x16x32_bf16(bfrag, afrag, acc[c], 0, 0, 0);
        }
    }

    int gr = rbase + r0 + m;
    if (gr < n) {
        float sc = dscale[gr];
#pragma unroll
        for (int c = 0; c < COLS / 16; c++) {
            uint2 pk;
            pk.x = pack_bf16(acc[c][0] * sc, acc[c][1] * sc);
            pk.y = pack_bf16(acc[c][2] * sc, acc[c][3] * sc);
            *(uint2*)&Cq[(size_t)gr * (COLS / 2) + c * 8 + q * 2] = pk;
        }
    }
}

// ---------- FUSED: aggregate layer-1 (D=128) + GEMM2 (128->64) ----------
// 512 threads = 32 quarter-waves = 32 nodes/block (R12 form, proven).
__global__ __launch_bounds__(512) void agg128_mm64(
    const uint* __restrict__ hq, const int* __restrict__ rec,
    const int4* __restrict__ meta, const float* __restrict__ dinv,
    const float* __restrict__ bias, const float* __restrict__ W2,
    uint* __restrict__ h2q, int n) {
    __shared__ ushort sWT[64 * 128];   // 16 KB
    __shared__ ushort sg[32 * 128];    // 8 KB
    int t = threadIdx.x;

    // stage W2^T (f32 -> bf16, XOR swizzle) — same pattern as gemm_mfma<64>
#pragma unroll
    for (int i = 0; i < 2; i++) {
        int u = t + 512 * i;          // 0..1023 = (kp, n4)
        int kp = u >> 4;
        int n4 = u & 15;
        int k = kp * 2;
        float4 w0 = *(const float4*)(W2 + (size_t)k * 64 + n4 * 4);
        float4 w1 = *(const float4*)(W2 + (size_t)(k + 1) * 64 + n4 * 4);
        int chunk = k >> 3;
        int sub = k & 7;
        const float* a0f = (const float*)&w0;
        const float* a1f = (const float*)&w1;
#pragma unroll
        for (int j = 0; j < 4; j++) {
            int nn = n4 * 4 + j;
            uint pk = pack_bf16(a0f[j], a1f[j]);
            *(uint*)&sWT[nn * 128 + (((chunk ^ (nn & 15)) << 3) + sub)] = pk;
        }
    }

    int qw = t >> 4;                  // 0..31 local node
    int fl = t & 15;                  // uint4 lane: features 8*fl .. 8*fl+7
    int nb0 = blockIdx.x * 32;
    int w = nb0 + qw;
    bool valid = w < n;
    int wsafe = valid ? w : 0;
    const uint4* h4 = (const uint4*)hq;   // row = 16 uint4

    int4 mt = meta[wsafe];
    int j0 = mt.x;
    int deg = valid ? mt.y : 0;
    float di = __int_as_float(mt.z);

    // self term (pre-scaled row, weight 1)
    uint4 qs = h4[(size_t)wsafe * 16 + fl];
    float a0 = bf16_lo(qs.x), a1 = bf16_hi(qs.x);
    float a2 = bf16_lo(qs.y), a3 = bf16_hi(qs.y);
    float a4 = bf16_lo(qs.z), a5 = bf16_hi(qs.z);
    float a6 = bf16_lo(qs.w), a7 = bf16_hi(qs.w);
    if (!valid) { a0 = a1 = a2 = a3 = a4 = a5 = a6 = a7 = 0.f; }

    const int* rp = rec + j0;
    int tt = 0;
    for (; tt + 8 <= deg; tt += 8) {
        int s[8]; uint4 q[8];
#pragma unroll
        for (int u = 0; u < 8; u++) s[u] = rp[tt + u];
#pragma unroll
        for (int u = 0; u < 8; u++) q[u] = h4[(size_t)s[u] * 16 + fl];
#pragma unroll
        for (int u = 0; u < 8; u++) {
            a0 += bf16_lo(q[u].x); a1 += bf16_hi(q[u].x);
            a2 += bf16_lo(q[u].y); a3 += bf16_hi(q[u].y);
            a4 += bf16_lo(q[u].z); a5 += bf16_hi(q[u].z);
            a6 += bf16_lo(q[u].w); a7 += bf16_hi(q[u].w);
        }
    }
    for (; tt + 2 <= deg; tt += 2) {
        int s0i = rp[tt], s1i = rp[tt + 1];
        uint4 q0 = h4[(size_t)s0i * 16 + fl];
        uint4 q1 = h4[(size_t)s1i * 16 + fl];
        a0 += bf16_lo(q0.x) + bf16_lo(q1.x);
        a1 += bf16_hi(q0.x) + bf16_hi(q1.x);
        a2 += bf16_lo(q0.y) + bf16_lo(q1.y);
        a3 += bf16_hi(q0.y) + bf16_hi(q1.y);
        a4 += bf16_lo(q0.z) + bf16_lo(q1.z);
        a5 += bf16_hi(q0.z) + bf16_hi(q1.z);
        a6 += bf16_lo(q0.w) + bf16_lo(q1.w);
        a7 += bf16_hi(q0.w) + bf16_hi(q1.w);
    }
    if (tt < deg) {
        int s = rp[tt];
        uint4 q0 = h4[(size_t)s * 16 + fl];
        a0 += bf16_lo(q0.x); a1 += bf16_hi(q0.x);
        a2 += bf16_lo(q0.y); a3 += bf16_hi(q0.y);
        a4 += bf16_lo(q0.z); a5 += bf16_hi(q0.z);
        a6 += bf16_lo(q0.w); a7 += bf16_hi(q0.w);
    }

    // g = relu(di*acc + b1) -> bf16 -> LDS (same swizzle as gemm_mfma staging)
    float4 bb0 = *(const float4*)&bias[8 * fl];
    float4 bb1 = *(const float4*)&bias[8 * fl + 4];
    uint4 pkv;
    pkv.x = pack_bf16(fmaxf(di * a0 + bb0.x, 0.f), fmaxf(di * a1 + bb0.y, 0.f));
    pkv.y = pack_bf16(fmaxf(di * a2 + bb0.z, 0.f), fmaxf(di * a3 + bb0.w, 0.f));
    pkv.z = pack_bf16(fmaxf(di * a4 + bb1.x, 0.f), fmaxf(di * a5 + bb1.y, 0.f));
    pkv.w = pack_bf16(fmaxf(di * a6 + bb1.z, 0.f), fmaxf(di * a7 + bb1.w, 0.f));
    *(uint4*)&sg[qw * 128 + ((fl ^ (qw & 15)) << 3)] = pkv;
    __syncthreads();

    // h2 = g @ W2 : 32 rows x 64 cols, 8 waves = 2 row-tiles x 4 col-tiles
    int wave = t >> 6;
    int lane = t & 63;
    int m = lane & 15;
    int qq = lane >> 4;
    int rt = wave >> 2;               // row tile 0..1
    int ct = wave & 3;                // col tile 0..3
    floatx4 acc = (floatx4){0.f, 0.f, 0.f, 0.f};
#pragma unroll
    for (int ks = 0; ks < 4; ks++) {
        int rr = rt * 16 + m;
        int ca = (ks * 4 + qq) ^ (rr & 15);
        short8 afrag = *(const short8*)&sg[rr * 128 + (ca << 3)];
        int nn = ct * 16 + m;
        int cb = (ks * 4 + qq) ^ (nn & 15);
        short8 bfrag = *(const short8*)&sWT[nn * 128 + (cb << 3)];
        acc = __builtin_amdgcn_mfma_f32_16x16x32_bf16(bfrag, afrag, acc, 0, 0, 0);
    }
    int gr = nb0 + rt * 16 + m;
    if (gr < n) {
        float sc = dinv[gr];          // pre-scale h2 rows for layer-2 gather
        uint2 pk;
        pk.x = pack_bf16(acc[0] * sc, acc[1] * sc);
        pk.y = pack_bf16(acc[2] * sc, acc[3] * sc);
        *(uint2*)&h2q[(size_t)gr * 32 + ct * 8 + qq * 2] = pk;
    }
}

// ---------- pull aggregation, D=64 (pre-scaled bf16 in, f32 out) ----------
// eighth-wave: 8 lanes x uint4 = 128B row (R12 form, proven).
__global__ __launch_bounds__(256) void aggregate64q(
    const uint* __restrict__ hq, const int* __restrict__ rec,
    const int4* __restrict__ meta, const float* __restrict__ bias,
    float* __restrict__ out, int n) {
    int gt = blockIdx.x * 256 + threadIdx.x;
    int w = gt >> 3;
    if (w >= n) return;
    int fl = gt & 7;                  // features 8*fl .. 8*fl+7

    int4 mt = meta[w];
    int j0 = mt.x;
    int deg = mt.y;
    float di = __int_as_float(mt.z);
    const uint4* h4 = (const uint4*)hq;   // row = 8 uint4

    uint4 qs = h4[(size_t)w * 8 + fl];
    float a0 = bf16_lo(qs.x), a1 = bf16_hi(qs.x);
    float a2 = bf16_lo(qs.y), a3 = bf16_hi(qs.y);
    float a4 = bf16_lo(qs.z), a5 = bf16_hi(qs.z);
    float a6 = bf16_lo(qs.w), a7 = bf16_hi(qs.w);

    const int* rp = rec + j0;
    int tt = 0;
    for (; tt + 8 <= deg; tt += 8) {
        int s[8]; uint4 q[8];
#pragma unroll
        for (int u = 0; u < 8; u++) s[u] = rp[tt + u];
#pragma unroll
        for (int u = 0; u < 8; u++) q[u] = h4[(size_t)s[u] * 8 + fl];
#pragma unroll
        for (int u = 0; u < 8; u++) {
            a0 += bf16_lo(q[u].x); a1 += bf16_hi(q[u].x);
            a2 += bf16_lo(q[u].y); a3 += bf16_hi(q[u].y);
            a4 += bf16_lo(q[u].z); a5 += bf16_hi(q[u].z);
            a6 += bf16_lo(q[u].w); a7 += bf16_hi(q[u].w);
        }
    }
    for (; tt + 2 <= deg; tt += 2) {
        int s0i = rp[tt], s1i = rp[tt + 1];
        uint4 q0 = h4[(size_t)s0i * 8 + fl];
        uint4 q1 = h4[(size_t)s1i * 8 + fl];
        a0 += bf16_lo(q0.x) + bf16_lo(q1.x);
        a1 += bf16_hi(q0.x) + bf16_hi(q1.x);
        a2 += bf16_lo(q0.y) + bf16_lo(q1.y);
        a3 += bf16_hi(q0.y) + bf16_hi(q1.y);
        a4 += bf16_lo(q0.z) + bf16_lo(q1.z);
        a5 += bf16_hi(q0.z) + bf16_hi(q1.z);
        a6 += bf16_lo(q0.w) + bf16_lo(q1.w);
        a7 += bf16_hi(q0.w) + bf16_hi(q1.w);
    }
    if (tt < deg) {
        int s = rp[tt];
        uint4 q0 = h4[(size_t)s * 8 + fl];
        a0 += bf16_lo(q0.x); a1 += bf16_hi(q0.x);
        a2 += bf16_lo(q0.y); a3 += bf16_hi(q0.y);
        a4 += bf16_lo(q0.z); a5 += bf16_hi(q0.z);
        a6 += bf16_lo(q0.w); a7 += bf16_hi(q0.w);
    }

    float4 bb0 = *(const float4*)&bias[8 * fl];
    float4 bb1 = *(const float4*)&bias[8 * fl + 4];
    float4 o0, o1;
    o0.x = di * a0 + bb0.x; o0.y = di * a1 + bb0.y;
    o0.z = di * a2 + bb0.z; o0.w = di * a3 + bb0.w;
    o1.x = di * a4 + bb1.x; o1.y = di * a5 + bb1.y;
    o1.z = di * a6 + bb1.z; o1.w = di * a7 + bb1.w;
    *(float4*)&out[(size_t)w * 64 + 8 * fl] = o0;
    *(float4*)&out[(size_t)w * 64 + 8 * fl + 4] = o1;
}

extern "C" void kernel_launch(void* const* d_in, const int* in_sizes, int n_in,
                              void* d_out, int out_size, void* d_ws, size_t ws_size,
                              hipStream_t stream) {
    const float* x = (const float*)d_in[0];
    const int* edge = (const int*)d_in[1];
    const float* W1 = (const float*)d_in[2];
    const float* b1 = (const float*)d_in[3];
    const float* W2 = (const float*)d_in[4];
    const float* b2 = (const float*)d_in[5];

    const int N = in_sizes[0] / 128;
    const int E = in_sizes[1] / 2;
    const int* src = edge;
    const int* dst = edge + E;
    const int NB = (N + (1 << BSH) - 1) >> BSH;   // coarse buckets (<= 512)

    // workspace carve-up (all chunks 16B-aligned for these sizes)
    char* p = (char*)d_ws;
    int* bfill = (int*)p;     p += NBMAX * 4;           // bucket fill counts
    float* dinv = (float*)p;  p += (size_t)N * 4;
    int4* meta = (int4*)p;    p += (size_t)N * 16;      // (start, deg, dinv, dinv^2)
    int* rec = (int*)p;       p += (size_t)E * 4;       // src per edge (CSR by dst)
    uint* staged = (uint*)p;  p += (size_t)NBMAX * BCAP * 4;  // fixed bucket regions
    uint* hq = (uint*)p;      p += (size_t)N * 64 * 4;  // dinv[r]*(x@W1), bf16 pairs
    uint* h2q = (uint*)p;     p += (size_t)N * 32 * 4;  // dinv[r]*h2, bf16 (64 feats)

    float* out = (float*)d_out;
    const int eblocks = (E + 2047) / 2048;

    // CSR build: 3 dispatches total (memset + partition + fine_csr)
    (void)hipMemsetAsync(bfill, 0, NBMAX * 4, stream);
    partition_kernel<<<eblocks, 256, 0, stream>>>(src, dst, bfill, staged, E, NB);
    fine_csr_kernel<<<NB, 256, 0, stream>>>(staged, bfill, meta, dinv, rec, N);

    const int gblocks = (N + 63) / 64;

    // layer 1 GEMM: hq = dinv .* (x @ W1) (bf16, pre-scaled rows)
    gemm_mfma<128, true><<<gblocks, 256, 0, stream>>>(x, W1, hq, dinv, N);
    // fused: g = relu(di*(sum of pre-scaled rows) + b1); h2q = dinv .* (g @ W2)
    agg128_mm64<<<(N + 31) / 32, 512, 0, stream>>>(hq, rec, meta, dinv, b1, W2, h2q, N);
    // layer 2 aggregation: out = di*(sum of pre-scaled h2 rows) + b2
    aggregate64q<<<(N * 8 + 255) / 256, 256, 0, stream>>>(h2q, rec, meta, b2, out, N);
}

// Round 8
// 267.934 us; speedup vs baseline: 1.6191x; 1.0260x over previous
//
#include <hip/hip_runtime.h>
#include <hip/hip_bf16.h>

// GCN 2-layer: h = relu(Anorm @ (x@W1) + b1); out = Anorm @ (h@W2) + b2
// R17 changes vs R16 (274.9us, best):
//  - MERGE partition + gemm1 into ONE dispatch (boundary ~6-7us each,
//    measured R15->R16). Blocks [0,eblocks) partition edges; blocks
//    [eblocks, eblocks+gblocks) run the MFMA GEMM. Shared 48KB LDS blob,
//    branch-carved. The two jobs are independent (gemm no longer needs
//    dinv) and use disjoint pipes -> overlap.
//  - hq is now RAW x@W1 (bf16). agg128 applies per-edge weights again
//    (R9 form: self=di^2, neighbor=dinv[s]*di; measured cost +2.5us).
//    h2q stays pre-scaled in agg128's epilogue -> aggregate64q unchanged.
//  - Chain: memset, part_gemm1, fine_csr, agg128_mm64, aggregate64q (5).

#define NTHREADS 256
#define BSH 8                 // bucket = dst >> 8 (256 nodes/bucket)
#define NBMAX 512
#define BCAP 5632             // fixed slots per bucket (mean 4096, +24 sigma)
#define FC_CAP 8192           // LDS edge cache per bucket

typedef unsigned int uint;
typedef unsigned short ushort;
typedef __attribute__((ext_vector_type(8))) short short8;
typedef __attribute__((ext_vector_type(4))) float floatx4;

__device__ __forceinline__ uint pack_bf16(float a, float b) {
    __hip_bfloat162 h = __float22bfloat162_rn(make_float2(a, b));
    return *reinterpret_cast<uint*>(&h);
}
__device__ __forceinline__ float bf16_lo(uint q) { return __uint_as_float(q << 16); }
__device__ __forceinline__ float bf16_hi(uint q) { return __uint_as_float(q & 0xffff0000u); }

// ---------- MERGED: edge partition (blocks < eblocks) + GEMM1 (rest) ----------
// partition: staged[b*BCAP + r] = (src<<8 | dst&255); bfill[b] += count.
// gemm: hq[r,128] = bf16(X[r,:] @ W1), UNSCALED.
__global__ __launch_bounds__(256) void part_gemm1(
    const int* __restrict__ src, const int* __restrict__ dst,
    int* __restrict__ bfill, uint* __restrict__ staged, int e, int nb, int eblocks,
    const float* __restrict__ X, const float* __restrict__ W1,
    uint* __restrict__ hq, int n) {
    __shared__ __align__(16) char smem[49152];
    int t = threadIdx.x;

    if ((int)blockIdx.x < eblocks) {
        // ---------------- partition branch (16 KB of smem) ----------------
        uint* eP = (uint*)smem;                    // 2048 uint  (8 KB)
        ushort* eB = (ushort*)(smem + 8192);       // 2048 ushort(4 KB)
        int* hist = (int*)(smem + 12288);          // 512 int   (2 KB)
        int* base = (int*)(smem + 14336);          // 512 int   (2 KB)
        int e0 = blockIdx.x * 2048;

        for (int b = t; b < nb; b += 256) hist[b] = 0;
        __syncthreads();
#pragma unroll
        for (int v = 0; v < 2; v++) {
            int li = t * 8 + v * 4;
            int gi = e0 + li;
            int4 s4, d4;
            if (gi + 3 < e) {
                s4 = *(const int4*)&src[gi];
                d4 = *(const int4*)&dst[gi];
            } else {
                const int* sp = &src[gi];
                const int* dp = &dst[gi];
                s4.x = (gi + 0 < e) ? sp[0] : 0;  d4.x = (gi + 0 < e) ? dp[0] : -1;
                s4.y = (gi + 1 < e) ? sp[1] : 0;  d4.y = (gi + 1 < e) ? dp[1] : -1;
                s4.z = (gi + 2 < e) ? sp[2] : 0;  d4.z = (gi + 2 < e) ? dp[2] : -1;
                s4.w = (gi + 3 < e) ? sp[3] : 0;  d4.w = (gi + 3 < e) ? dp[3] : -1;
            }
            uint4 p4;
            p4.x = ((uint)s4.x << 8) | ((uint)d4.x & 255u);
            p4.y = ((uint)s4.y << 8) | ((uint)d4.y & 255u);
            p4.z = ((uint)s4.z << 8) | ((uint)d4.z & 255u);
            p4.w = ((uint)s4.w << 8) | ((uint)d4.w & 255u);
            *(uint4*)&eP[li] = p4;
            eB[li + 0] = (d4.x >= 0) ? (ushort)(d4.x >> BSH) : (ushort)0xFFFF;
            eB[li + 1] = (d4.y >= 0) ? (ushort)(d4.y >> BSH) : (ushort)0xFFFF;
            eB[li + 2] = (d4.z >= 0) ? (ushort)(d4.z >> BSH) : (ushort)0xFFFF;
            eB[li + 3] = (d4.w >= 0) ? (ushort)(d4.w >> BSH) : (ushort)0xFFFF;
            if (d4.x >= 0) atomicAdd(&hist[d4.x >> BSH], 1);
            if (d4.y >= 0) atomicAdd(&hist[d4.y >> BSH], 1);
            if (d4.z >= 0) atomicAdd(&hist[d4.z >> BSH], 1);
            if (d4.w >= 0) atomicAdd(&hist[d4.w >> BSH], 1);
        }
        __syncthreads();
        for (int b = t; b < nb; b += 256) {
            int v = hist[b];
            base[b] = v ? (b * BCAP + atomicAdd(&bfill[b], v)) : 0;
            hist[b] = 0;   // reset for rank pass
        }
        __syncthreads();
#pragma unroll
        for (int i = 0; i < 8; i++) {
            int li = t + i * 256;
            ushort bb = eB[li];
            if (bb != (ushort)0xFFFF) {
                int r = atomicAdd(&hist[bb], 1);
                staged[base[bb] + r] = eP[li];
            }
        }
    } else {
        // ---------------- GEMM1 branch (48 KB of smem) ----------------
        ushort* sX = (ushort*)smem;                // 64*128 (16 KB)
        ushort* sWT = (ushort*)(smem + 16384);     // 128*128 (32 KB)
        int rbase = ((int)blockIdx.x - eblocks) * 64;

#pragma unroll
        for (int i = 0; i < 8; i++) {
            int f = t + 256 * i;
            int r = f >> 5;
            int c4 = f & 31;
            float4 v = make_float4(0.f, 0.f, 0.f, 0.f);
            int gr = rbase + r;
            if (gr < n) v = *(const float4*)(X + (size_t)gr * 128 + c4 * 4);
            uint lo = pack_bf16(v.x, v.y);
            uint hi = pack_bf16(v.z, v.w);
            int chunk = c4 >> 1;
            int sub = (c4 & 1) * 4;
            int off = r * 128 + (((chunk ^ (r & 15)) << 3) + sub);
            *(uint2*)&sX[off] = make_uint2(lo, hi);
        }
#pragma unroll
        for (int i = 0; i < 8; i++) {
            int u = t + 256 * i;           // (kp, n4), kp=u/32, n4=u%32
            int kp = u >> 5;
            int n4 = u & 31;
            int k = kp * 2;
            float4 w0 = *(const float4*)(W1 + (size_t)k * 128 + n4 * 4);
            float4 w1 = *(const float4*)(W1 + (size_t)(k + 1) * 128 + n4 * 4);
            int chunk = k >> 3;
            int sub = k & 7;
            const float* a0 = (const float*)&w0;
            const float* a1 = (const float*)&w1;
#pragma unroll
            for (int j = 0; j < 4; j++) {
                int nn = n4 * 4 + j;
                uint pk = pack_bf16(a0[j], a1[j]);
                int off = nn * 128 + (((chunk ^ (nn & 15)) << 3) + sub);
                *(uint*)&sWT[off] = pk;
            }
        }
        __syncthreads();

        int lane = t & 63;
        int wave = t >> 6;
        int m = lane & 15;
        int q = lane >> 4;
        int r0 = wave * 16;

        floatx4 acc[8];
#pragma unroll
        for (int c = 0; c < 8; c++) acc[c] = (floatx4){0.f, 0.f, 0.f, 0.f};

#pragma unroll
        for (int ks = 0; ks < 4; ks++) {
            int rr = r0 + m;
            int ca = (ks * 4 + q) ^ (rr & 15);
            short8 afrag = *(const short8*)&sX[rr * 128 + (ca << 3)];
#pragma unroll
            for (int c = 0; c < 8; c++) {
                int nn = c * 16 + m;
                int cb = (ks * 4 + q) ^ (nn & 15);
                short8 bfrag = *(const short8*)&sWT[nn * 128 + (cb << 3)];
                acc[c] = __builtin_amdgcn_mfma_f32_16x16x32_bf16(bfrag, afrag, acc[c], 0, 0, 0);
            }
        }

        int gr = rbase + r0 + m;
        if (gr < n) {
#pragma unroll
            for (int c = 0; c < 8; c++) {
                uint2 pk;
                pk.x = pack_bf16(acc[c][0], acc[c][1]);
                pk.y = pack_bf16(acc[c][2], acc[c][3]);
                *(uint2*)&hq[(size_t)gr * 64 + c * 8 + q * 2] = pk;
            }
        }
    }
}

// ---------- per-bucket fused CSR: dense offset by bfill reduction,
//            count+scan -> meta/dinv, LDS-cached fill ----------
__global__ __launch_bounds__(256) void fine_csr_kernel(
    const uint* __restrict__ staged, const int* __restrict__ bfill,
    int4* __restrict__ meta, float* __restrict__ dinv,
    int* __restrict__ rec, int n) {
    __shared__ uint eL[FC_CAP];      // 32 KB edge cache
    __shared__ int lcnt[256];
    __shared__ int tsum[256];
    __shared__ int red[256];
    int b = blockIdx.x;
    int t = threadIdx.x;

    // s0 = dense start = sum_{j<b} bfill[j]  (all blocks compute their own)
    int part = 0;
    for (int j = t; j < b; j += 256) part += bfill[j];
    red[t] = part;
    lcnt[t] = 0;
    __syncthreads();
    for (int off = 128; off > 0; off >>= 1) {
        if (t < off) red[t] += red[t + off];
        __syncthreads();
    }
    int s0 = red[0];
    int m = bfill[b];

    int sb = b * BCAP;               // sparse (staged) base for this bucket
    for (int i = t; i < m; i += 256) {
        uint pk = staged[sb + i];
        eL[i] = pk;                  // m <= BCAP < FC_CAP always
        atomicAdd(&lcnt[pk & 255u], 1);
    }
    __syncthreads();
    int v = lcnt[t];
    tsum[t] = v;
    __syncthreads();
    int x = v;
    for (int off = 1; off < 256; off <<= 1) {
        int y = (t >= off) ? tsum[t - off] : 0;
        __syncthreads();
        x += y;
        tsum[t] = x;
        __syncthreads();
    }
    int excl = x - v;
    int node = (b << BSH) + t;
    if (node < n) {
        float di = rsqrtf((float)v + 1.0f);
        dinv[node] = di;
        meta[node] = make_int4(s0 + excl, v, __float_as_int(di), __float_as_int(di * di));
    }
    lcnt[t] = s0 + excl;             // repurpose as absolute cursor
    __syncthreads();
    // fill: rec[pos] = src (edges come from LDS cache)
    for (int i = t; i < m; i += 256) {
        uint pk = eL[i];
        int pos = atomicAdd(&lcnt[pk & 255u], 1);
        rec[pos] = (int)(pk >> 8);
    }
}

// ---------- FUSED: aggregate layer-1 (D=128, per-edge weights) + GEMM2 ----------
// 512 threads = 32 quarter-waves = 32 nodes/block. hq is RAW; weights
// applied per edge (self=di^2, neighbor=dinv[s]*di; dinv is L2-resident
// broadcast). h2 output pre-scaled by dinv[row] for layer-2 gather.
__global__ __launch_bounds__(512) void agg128_mm64(
    const uint* __restrict__ hq, const int* __restrict__ rec,
    const int4* __restrict__ meta, const float* __restrict__ dinv,
    const float* __restrict__ bias, const float* __restrict__ W2,
    uint* __restrict__ h2q, int n) {
    __shared__ ushort sWT[64 * 128];   // 16 KB
    __shared__ ushort sg[32 * 128];    // 8 KB
    int t = threadIdx.x;

    // stage W2^T (f32 -> bf16, XOR swizzle)
#pragma unroll
    for (int i = 0; i < 2; i++) {
        int u = t + 512 * i;          // 0..1023 = (kp, n4)
        int kp = u >> 4;
        int n4 = u & 15;
        int k = kp * 2;
        float4 w0 = *(const float4*)(W2 + (size_t)k * 64 + n4 * 4);
        float4 w1 = *(const float4*)(W2 + (size_t)(k + 1) * 64 + n4 * 4);
        int chunk = k >> 3;
        int sub = k & 7;
        const float* a0f = (const float*)&w0;
        const float* a1f = (const float*)&w1;
#pragma unroll
        for (int j = 0; j < 4; j++) {
            int nn = n4 * 4 + j;
            uint pk = pack_bf16(a0f[j], a1f[j]);
            *(uint*)&sWT[nn * 128 + (((chunk ^ (nn & 15)) << 3) + sub)] = pk;
        }
    }

    int qw = t >> 4;                  // 0..31 local node
    int fl = t & 15;                  // uint4 lane: features 8*fl .. 8*fl+7
    int nb0 = blockIdx.x * 32;
    int w = nb0 + qw;
    bool valid = w < n;
    int wsafe = valid ? w : 0;
    const uint4* h4 = (const uint4*)hq;   // row = 16 uint4

    int4 mt = meta[wsafe];
    int j0 = mt.x;
    int deg = valid ? mt.y : 0;
    float di = __int_as_float(mt.z);
    float swq = valid ? __int_as_float(mt.w) : 0.f;   // di^2

    // self term (raw row, weight di^2)
    uint4 qs = h4[(size_t)wsafe * 16 + fl];
    float a0 = bf16_lo(qs.x) * swq, a1 = bf16_hi(qs.x) * swq;
    float a2 = bf16_lo(qs.y) * swq, a3 = bf16_hi(qs.y) * swq;
    float a4 = bf16_lo(qs.z) * swq, a5 = bf16_hi(qs.z) * swq;
    float a6 = bf16_lo(qs.w) * swq, a7 = bf16_hi(qs.w) * swq;

    const int* rp = rec + j0;
    int tt = 0;
    for (; tt + 8 <= deg; tt += 8) {
        int s[8]; float wf[8]; uint4 q[8];
#pragma unroll
        for (int u = 0; u < 8; u++) s[u] = rp[tt + u];
#pragma unroll
        for (int u = 0; u < 8; u++) wf[u] = dinv[s[u]] * di;
#pragma unroll
        for (int u = 0; u < 8; u++) q[u] = h4[(size_t)s[u] * 16 + fl];
#pragma unroll
        for (int u = 0; u < 8; u++) {
            a0 += bf16_lo(q[u].x) * wf[u]; a1 += bf16_hi(q[u].x) * wf[u];
            a2 += bf16_lo(q[u].y) * wf[u]; a3 += bf16_hi(q[u].y) * wf[u];
            a4 += bf16_lo(q[u].z) * wf[u]; a5 += bf16_hi(q[u].z) * wf[u];
            a6 += bf16_lo(q[u].w) * wf[u]; a7 += bf16_hi(q[u].w) * wf[u];
        }
    }
    for (; tt + 2 <= deg; tt += 2) {
        int s0i = rp[tt], s1i = rp[tt + 1];
        float w0v = dinv[s0i] * di, w1v = dinv[s1i] * di;
        uint4 q0 = h4[(size_t)s0i * 16 + fl];
        uint4 q1 = h4[(size_t)s1i * 16 + fl];
        a0 += bf16_lo(q0.x) * w0v + bf16_lo(q1.x) * w1v;
        a1 += bf16_hi(q0.x) * w0v + bf16_hi(q1.x) * w1v;
        a2 += bf16_lo(q0.y) * w0v + bf16_lo(q1.y) * w1v;
        a3 += bf16_hi(q0.y) * w0v + bf16_hi(q1.y) * w1v;
        a4 += bf16_lo(q0.z) * w0v + bf16_lo(q1.z) * w1v;
        a5 += bf16_hi(q0.z) * w0v + bf16_hi(q1.z) * w1v;
        a6 += bf16_lo(q0.w) * w0v + bf16_lo(q1.w) * w1v;
        a7 += bf16_hi(q0.w) * w0v + bf16_hi(q1.w) * w1v;
    }
    if (tt < deg) {
        int s = rp[tt];
        float wv = dinv[s] * di;
        uint4 q0 = h4[(size_t)s * 16 + fl];
        a0 += bf16_lo(q0.x) * wv; a1 += bf16_hi(q0.x) * wv;
        a2 += bf16_lo(q0.y) * wv; a3 += bf16_hi(q0.y) * wv;
        a4 += bf16_lo(q0.z) * wv; a5 += bf16_hi(q0.z) * wv;
        a6 += bf16_lo(q0.w) * wv; a7 += bf16_hi(q0.w) * wv;
    }

    // g = relu(acc + b1) -> bf16 -> LDS (weights fully applied per edge)
    float4 bb0 = *(const float4*)&bias[8 * fl];
    float4 bb1 = *(const float4*)&bias[8 * fl + 4];
    uint4 pkv;
    pkv.x = pack_bf16(fmaxf(a0 + bb0.x, 0.f), fmaxf(a1 + bb0.y, 0.f));
    pkv.y = pack_bf16(fmaxf(a2 + bb0.z, 0.f), fmaxf(a3 + bb0.w, 0.f));
    pkv.z = pack_bf16(fmaxf(a4 + bb1.x, 0.f), fmaxf(a5 + bb1.y, 0.f));
    pkv.w = pack_bf16(fmaxf(a6 + bb1.z, 0.f), fmaxf(a7 + bb1.w, 0.f));
    *(uint4*)&sg[qw * 128 + ((fl ^ (qw & 15)) << 3)] = pkv;
    __syncthreads();

    // h2 = g @ W2 : 32 rows x 64 cols, 8 waves = 2 row-tiles x 4 col-tiles
    int wave = t >> 6;
    int lane = t & 63;
    int m = lane & 15;
    int qq = lane >> 4;
    int rt = wave >> 2;               // row tile 0..1
    int ct = wave & 3;                // col tile 0..3
    floatx4 acc = (floatx4){0.f, 0.f, 0.f, 0.f};
#pragma unroll
    for (int ks = 0; ks < 4; ks++) {
        int rr = rt * 16 + m;
        int ca = (ks * 4 + qq) ^ (rr & 15);
        short8 afrag = *(const short8*)&sg[rr * 128 + (ca << 3)];
        int nn = ct * 16 + m;
        int cb = (ks * 4 + qq) ^ (nn & 15);
        short8 bfrag = *(const short8*)&sWT[nn * 128 + (cb << 3)];
        acc = __builtin_amdgcn_mfma_f32_16x16x32_bf16(bfrag, afrag, acc, 0, 0, 0);
    }
    int gr = nb0 + rt * 16 + m;
    if (gr < n) {
        float sc = dinv[gr];          // pre-scale h2 rows for layer-2 gather
        uint2 pk;
        pk.x = pack_bf16(acc[0] * sc, acc[1] * sc);
        pk.y = pack_bf16(acc[2] * sc, acc[3] * sc);
        *(uint2*)&h2q[(size_t)gr * 32 + ct * 8 + qq * 2] = pk;
    }
}

// ---------- pull aggregation, D=64 (pre-scaled bf16 in, f32 out) ----------
// eighth-wave: 8 lanes x uint4 = 128B row (proven form, unchanged).
__global__ __launch_bounds__(256) void aggregate64q(
    const uint* __restrict__ hq, const int* __restrict__ rec,
    const int4* __restrict__ meta, const float* __restrict__ bias,
    float* __restrict__ out, int n) {
    int gt = blockIdx.x * 256 + threadIdx.x;
    int w = gt >> 3;
    if (w >= n) return;
    int fl = gt & 7;                  // features 8*fl .. 8*fl+7

    int4 mt = meta[w];
    int j0 = mt.x;
    int deg = mt.y;
    float di = __int_as_float(mt.z);
    const uint4* h4 = (const uint4*)hq;   // row = 8 uint4

    uint4 qs = h4[(size_t)w * 8 + fl];
    float a0 = bf16_lo(qs.x), a1 = bf16_hi(qs.x);
    float a2 = bf16_lo(qs.y), a3 = bf16_hi(qs.y);
    float a4 = bf16_lo(qs.z), a5 = bf16_hi(qs.z);
    float a6 = bf16_lo(qs.w), a7 = bf16_hi(qs.w);

    const int* rp = rec + j0;
    int tt = 0;
    for (; tt + 8 <= deg; tt += 8) {
        int s[8]; uint4 q[8];
#pragma unroll
        for (int u = 0; u < 8; u++) s[u] = rp[tt + u];
#pragma unroll
        for (int u = 0; u < 8; u++) q[u] = h4[(size_t)s[u] * 8 + fl];
#pragma unroll
        for (int u = 0; u < 8; u++) {
            a0 += bf16_lo(q[u].x); a1 += bf16_hi(q[u].x);
            a2 += bf16_lo(q[u].y); a3 += bf16_hi(q[u].y);
            a4 += bf16_lo(q[u].z); a5 += bf16_hi(q[u].z);
            a6 += bf16_lo(q[u].w); a7 += bf16_hi(q[u].w);
        }
    }
    for (; tt + 2 <= deg; tt += 2) {
        int s0i = rp[tt], s1i = rp[tt + 1];
        uint4 q0 = h4[(size_t)s0i * 8 + fl];
        uint4 q1 = h4[(size_t)s1i * 8 + fl];
        a0 += bf16_lo(q0.x) + bf16_lo(q1.x);
        a1 += bf16_hi(q0.x) + bf16_hi(q1.x);
        a2 += bf16_lo(q0.y) + bf16_lo(q1.y);
        a3 += bf16_hi(q0.y) + bf16_hi(q1.y);
        a4 += bf16_lo(q0.z) + bf16_lo(q1.z);
        a5 += bf16_hi(q0.z) + bf16_hi(q1.z);
        a6 += bf16_lo(q0.w) + bf16_lo(q1.w);
        a7 += bf16_hi(q0.w) + bf16_hi(q1.w);
    }
    if (tt < deg) {
        int s = rp[tt];
        uint4 q0 = h4[(size_t)s * 8 + fl];
        a0 += bf16_lo(q0.x); a1 += bf16_hi(q0.x);
        a2 += bf16_lo(q0.y); a3 += bf16_hi(q0.y);
        a4 += bf16_lo(q0.z); a5 += bf16_hi(q0.z);
        a6 += bf16_lo(q0.w); a7 += bf16_hi(q0.w);
    }

    float4 bb0 = *(const float4*)&bias[8 * fl];
    float4 bb1 = *(const float4*)&bias[8 * fl + 4];
    float4 o0, o1;
    o0.x = di * a0 + bb0.x; o0.y = di * a1 + bb0.y;
    o0.z = di * a2 + bb0.z; o0.w = di * a3 + bb0.w;
    o1.x = di * a4 + bb1.x; o1.y = di * a5 + bb1.y;
    o1.z = di * a6 + bb1.z; o1.w = di * a7 + bb1.w;
    *(float4*)&out[(size_t)w * 64 + 8 * fl] = o0;
    *(float4*)&out[(size_t)w * 64 + 8 * fl + 4] = o1;
}

extern "C" void kernel_launch(void* const* d_in, const int* in_sizes, int n_in,
                              void* d_out, int out_size, void* d_ws, size_t ws_size,
                              hipStream_t stream) {
    const float* x = (const float*)d_in[0];
    const int* edge = (const int*)d_in[1];
    const float* W1 = (const float*)d_in[2];
    const float* b1 = (const float*)d_in[3];
    const float* W2 = (const float*)d_in[4];
    const float* b2 = (const float*)d_in[5];

    const int N = in_sizes[0] / 128;
    const int E = in_sizes[1] / 2;
    const int* src = edge;
    const int* dst = edge + E;
    const int NB = (N + (1 << BSH) - 1) >> BSH;   // coarse buckets (<= 512)

    // workspace carve-up (all chunks 16B-aligned for these sizes)
    char* p = (char*)d_ws;
    int* bfill = (int*)p;     p += NBMAX * 4;           // bucket fill counts
    float* dinv = (float*)p;  p += (size_t)N * 4;
    int4* meta = (int4*)p;    p += (size_t)N * 16;      // (start, deg, dinv, dinv^2)
    int* rec = (int*)p;       p += (size_t)E * 4;       // src per edge (CSR by dst)
    uint* staged = (uint*)p;  p += (size_t)NBMAX * BCAP * 4;  // fixed bucket regions
    uint* hq = (uint*)p;      p += (size_t)N * 64 * 4;  // RAW x@W1, bf16 pairs
    uint* h2q = (uint*)p;     p += (size_t)N * 32 * 4;  // dinv[r]*h2, bf16 (64 feats)

    float* out = (float*)d_out;
    const int eblocks = (E + 2047) / 2048;
    const int gblocks = (N + 63) / 64;

    (void)hipMemsetAsync(bfill, 0, NBMAX * 4, stream);
    // merged: edge partition + layer-1 GEMM (independent block families)
    part_gemm1<<<eblocks + gblocks, 256, 0, stream>>>(
        src, dst, bfill, staged, E, NB, eblocks, x, W1, hq, N);
    fine_csr_kernel<<<NB, 256, 0, stream>>>(staged, bfill, meta, dinv, rec, N);
    // fused: g = relu(sum of weighted raw rows + b1); h2q = dinv .* (g @ W2)
    agg128_mm64<<<(N + 31) / 32, 512, 0, stream>>>(hq, rec, meta, dinv, b1, W2, h2q, N);
    // layer 2 aggregation: out = di*(sum of pre-scaled h2 rows) + b2
    aggregate64q<<<(N * 8 + 255) / 256, 256, 0, stream>>>(h2q, rec, meta, b2, out, N);
}